// Round 1
// 271.890 us; speedup vs baseline: 1.0138x; 1.0138x over previous
//
#include <hip/hip_runtime.h>
#include <hip/hip_bf16.h>
#include <hip/hip_fp16.h>

// ---------- common types ----------
typedef __attribute__((ext_vector_type(8))) short bf16x8;      // 8 bf16 = 4 VGPR (MFMA A/B frag)
typedef __attribute__((ext_vector_type(8))) _Float16 f16x8;    // 8 f16  = 4 VGPR (MFMA A/B frag)
typedef __attribute__((ext_vector_type(4))) float f32x4;       // MFMA C/D frag
typedef __attribute__((ext_vector_type(8))) short short8;      // 16B chunk

__device__ __forceinline__ short f2bf(float x) {
    unsigned u = __builtin_bit_cast(unsigned, x);
    u += 0x7fffu + ((u >> 16) & 1u);          // RNE
    return (short)(u >> 16);
}

// async global->LDS, 16B per lane. lds dst must be wave-uniform base; HW scatters lane*16.
__device__ __forceinline__ void load_lds16(const void* g, void* l) {
    __builtin_amdgcn_global_load_lds((const __attribute__((address_space(1))) unsigned int*)g,
                                     (__attribute__((address_space(3))) unsigned int*)l, 16, 0, 0);
}

// ---------- K0: fused converts ----------
__global__ void convert_qkv(const float* __restrict__ q, const float* __restrict__ k,
                            const float* __restrict__ v, short* __restrict__ qo,
                            short* __restrict__ ko, short* __restrict__ vo) {
    int i = blockIdx.x * 256 + threadIdx.x;   // 1048576 float4 per tensor, grid (4096,3)
    const float* s = blockIdx.y == 0 ? q : blockIdx.y == 1 ? k : v;
    short* d = blockIdx.y == 0 ? qo : blockIdx.y == 1 ? ko : vo;
    float4 val = reinterpret_cast<const float4*>(s)[i];
    short4 o; o.x = f2bf(val.x); o.y = f2bf(val.y); o.z = f2bf(val.z); o.w = f2bf(val.w);
    reinterpret_cast<short4*>(d)[i] = o;
}

__global__ void convert_w4(const float* __restrict__ w0, const float* __restrict__ w1,
                           const float* __restrict__ w2, const float* __restrict__ w3,
                           short* __restrict__ o0, short* __restrict__ o1,
                           short* __restrict__ o2, short* __restrict__ o3) {
    int i = blockIdx.x * 256 + threadIdx.x;   // 262144 float4 per tensor, grid (1024,4)
    const float* s = blockIdx.y == 0 ? w0 : blockIdx.y == 1 ? w1 : blockIdx.y == 2 ? w2 : w3;
    short* d = blockIdx.y == 0 ? o0 : blockIdx.y == 1 ? o1 : blockIdx.y == 2 ? o2 : o3;
    float4 val = reinterpret_cast<const float4*>(s)[i];
    short4 o; o.x = f2bf(val.x); o.y = f2bf(val.y); o.z = f2bf(val.z); o.w = f2bf(val.w);
    reinterpret_cast<short4*>(d)[i] = o;
}

__global__ void convert_f32_f16(const float* __restrict__ src, _Float16* __restrict__ dst, int n) {
    int i = blockIdx.x * blockDim.x + threadIdx.x;
    if (i < n) dst[i] = (_Float16)src[i];
}

// ---------- K1: geometry bias via MFMA projection; stores g (f16, [b][h][n][m]) ----------
__global__ void geom_kernel2(const float* __restrict__ boxes, const _Float16* __restrict__ Wgh,
                             const float* __restrict__ bg, __half* __restrict__ G) {
    const int tid = threadIdx.x;
    const int wave = tid >> 6, lane = tid & 63, quad = lane >> 4, l16 = lane & 15;
    const int m0 = blockIdx.x * 64;
    const int n = blockIdx.y;
    const int b = blockIdx.z;

    __shared__ __align__(16) _Float16 feat[4][16][72];
    __shared__ __align__(16) _Float16 gbuf[16][68];

    const int p = lane >> 2, c = lane & 3;
    const int m = m0 + wave * 16 + p;

    float4 bn = reinterpret_cast<const float4*>(boxes)[b * 512 + n];
    float4 bm = reinterpret_cast<const float4*>(boxes)[b * 512 + m];
    float cxn = (bn.x + bn.z) * 0.5f, cyn = (bn.y + bn.w) * 0.5f;
    float wn = bn.z - bn.x + 1.0f, hn = bn.w - bn.y + 1.0f;
    float cxm = (bm.x + bm.z) * 0.5f, cym = (bm.y + bm.w) * 0.5f;
    float wm = bm.z - bm.x + 1.0f, hm = bm.w - bm.y + 1.0f;

    float r;
    if (c == 0)      r = fmaxf(fabsf((cxn - cxm) / wn), 1e-3f);
    else if (c == 1) r = fmaxf(fabsf((cyn - cym) / hn), 1e-3f);
    else if (c == 2) r = wn / wm;
    else             r = hn / hm;
    float pos = __logf(r) * 100.0f;

    const float dm[8] = {1.0f, 0.42169651f, 0.17782794f, 0.07498942f,
                         0.03162278f, 0.01333521f, 0.00562341f, 0.00237137f};
    f16x8 sv8, cv8;
    #pragma unroll
    for (int f = 0; f < 8; ++f) {
        float th = pos * dm[f];
        sv8[f] = (_Float16)__sinf(th);
        cv8[f] = (_Float16)__cosf(th);
    }
    *(f16x8*)&feat[wave][p][c * 8]      = sv8;
    *(f16x8*)&feat[wave][p][32 + c * 8] = cv8;

    __syncthreads();

    f16x8 a0 = *(const f16x8*)&feat[wave][l16][quad * 8];
    f16x8 a1 = *(const f16x8*)&feat[wave][l16][32 + quad * 8];
    f16x8 b0 = *(const f16x8*)(Wgh + l16 * 64 + quad * 8);
    f16x8 b1 = *(const f16x8*)(Wgh + l16 * 64 + 32 + quad * 8);
    f32x4 acc = (f32x4){0.f, 0.f, 0.f, 0.f};
    acc = __builtin_amdgcn_mfma_f32_16x16x32_f16(a0, b0, acc, 0, 0, 0);
    acc = __builtin_amdgcn_mfma_f32_16x16x32_f16(a1, b1, acc, 0, 0, 0);

    float bgv = bg[l16];
    #pragma unroll
    for (int rr = 0; rr < 4; ++rr) {
        float g = fmaxf(acc[rr] + bgv, 1e-6f);        // relu + clip; store g itself
        gbuf[l16][wave * 16 + quad * 4 + rr] = (_Float16)g;
    }
    __syncthreads();

    const int h = tid >> 4, seg = tid & 15;
    ushort4 v = *(const ushort4*)&gbuf[h][seg * 4];
    *(ushort4*)&G[((long)((b * 16 + h) * 512 + n)) * 512 + m0 + seg * 4] = v;
}

// ---------- K2: ALL projections, m97-style 128x128 tiles, 768 blocks (3/CU) ----------
// blocks [0,512):   Q/K proj  z=bid>>8: C[tok][out] = X . W^T  (bf16, col bias)
// blocks [512,768): V proj            : C[out][tok] = Wv . X^T (f16 Vt, row bias)
// 4 waves in 2x2; each wave owns a 64x64 sub-tile = acc[4][4] 16x16 frags.
// 16 MFMA per 2-barrier K-step (vs 8 in the old 128x64 version -> MfmaUtil 18%).
__global__ __launch_bounds__(256, 3)
void proj_all3(const short* __restrict__ qkbf, const short* __restrict__ wqkb,
               const short* __restrict__ wvb, const short* __restrict__ vbf,
               const float* __restrict__ bq, const float* __restrict__ bk,
               const float* __restrict__ bv,
               short* __restrict__ QKh, _Float16* __restrict__ Vt) {
    __shared__ __align__(16) short As[4096];   // [128][32]
    __shared__ __align__(16) short Bs[4096];   // [128][32]
    const int tid = threadIdx.x;
    const int wave = tid >> 6, lane = tid & 63, quad = lane >> 4, l16 = lane & 15;
    const int bid = blockIdx.x;

    const short *Ap, *Bp;
    int m0, n0, z = 0;
    bool isV = bid >= 512;
    if (!isV) {
        z = bid >> 8;
        int t = bid & 255;
        n0 = (t & 7) * 128; m0 = (t >> 3) * 128;
        Ap = qkbf + (long)z * 4194304 + (long)m0 * 1024;
        Bp = wqkb + (long)z * 1048576 + (long)n0 * 1024;
    } else {
        int t = bid - 512;
        n0 = (t & 31) * 128; m0 = (t >> 5) * 128;
        Ap = wvb + (long)m0 * 1024;
        Bp = vbf + (long)n0 * 1024;
    }

    f32x4 acc[4][4];
    #pragma unroll
    for (int mg = 0; mg < 4; ++mg)
        #pragma unroll
        for (int ng = 0; ng < 4; ++ng) acc[mg][ng] = (f32x4){0.f, 0.f, 0.f, 0.f};

    // staging: 256 threads x 16B = 4KB per issue; A/B tiles are 8KB each -> 2 issues each
    const int r0 = tid >> 2, kk = (tid & 3) * 8;
    const short* ga0 = Ap + (long)r0 * 1024 + kk;
    const short* ga1 = Ap + (long)(64 + r0) * 1024 + kk;
    const short* gb0 = Bp + (long)r0 * 1024 + kk;
    const short* gb1 = Bp + (long)(64 + r0) * 1024 + kk;
    short* la0 = As + wave * 512;
    short* la1 = As + 2048 + wave * 512;
    short* lb0 = Bs + wave * 512;
    short* lb1 = Bs + 2048 + wave * 512;

    const int wr = wave >> 1, wc = wave & 1;   // 2x2 wave grid, 64x64 per wave

    for (int k0 = 0; k0 < 1024; k0 += 32) {
        load_lds16(ga0 + k0, la0);
        load_lds16(ga1 + k0, la1);
        load_lds16(gb0 + k0, lb0);
        load_lds16(gb1 + k0, lb1);
        __syncthreads();
        bf16x8 a[4], bb[4];
        #pragma unroll
        for (int g = 0; g < 4; ++g)
            a[g] = *(const bf16x8*)&As[(wr * 64 + g * 16 + l16) * 32 + quad * 8];
        #pragma unroll
        for (int g = 0; g < 4; ++g)
            bb[g] = *(const bf16x8*)&Bs[(wc * 64 + g * 16 + l16) * 32 + quad * 8];
        #pragma unroll
        for (int mg = 0; mg < 4; ++mg)
            #pragma unroll
            for (int ng = 0; ng < 4; ++ng)
                acc[mg][ng] = __builtin_amdgcn_mfma_f32_16x16x32_bf16(a[mg], bb[ng], acc[mg][ng], 0, 0, 0);
        __syncthreads();
    }

    #pragma unroll
    for (int mg = 0; mg < 4; ++mg)
        #pragma unroll
        for (int ng = 0; ng < 4; ++ng)
            #pragma unroll
            for (int r = 0; r < 4; ++r) {
                int row = m0 + wr * 64 + mg * 16 + quad * 4 + r;
                int col = n0 + wc * 64 + ng * 16 + l16;
                if (!isV) {
                    float v = acc[mg][ng][r] + (z ? bk[col] : bq[col]);
                    QKh[(long)z * 4194304 + (long)row * 1024 + col] = f2bf(v);
                } else {
                    float v = acc[mg][ng][r] + bv[row];
                    int bcol = col >> 9, lc = col & 511;    // token -> (batch, local)
                    Vt[(long)bcol * 524288 + (long)row * 512 + lc] = (_Float16)v;
                }
            }
}

// ---------- K3: flash attention, m97-style cooperative LDS staging ----------
__global__ __launch_bounds__(256, 4)
void flash_attn6(const short* __restrict__ Q, const short* __restrict__ Kh,
                 const _Float16* __restrict__ Vt, const __half* __restrict__ G,
                 short* __restrict__ O) {
    const int tid = threadIdx.x;
    const int wave = tid >> 6, lane = tid & 63, quad = lane >> 4, l16 = lane & 15;
    const int qt = blockIdx.x, h = blockIdx.y, b = blockIdx.z;

    __shared__ __align__(16) short    Ks[64][72];        // [kv][d]
    __shared__ __align__(16) _Float16 Vs[64][72];        // [d][kv]
    __shared__ __align__(16) _Float16 Gs[64][72];        // [q][kv]
    __shared__ __align__(16) _Float16 Pbuf[4][16][72];   // per-wave private

    const int qrow = qt * 64 + wave * 16;
    const long qoff = ((long)(b * 512 + qrow + l16)) * 1024 + h * 64 + quad * 8;
    bf16x8 aq0 = *(const bf16x8*)(Q + qoff);
    bf16x8 aq1 = *(const bf16x8*)(Q + qoff + 32);

    const int sr0 = tid >> 3,         sc0 = (tid & 7) * 8;
    const int sr1 = (tid + 256) >> 3, sc1 = ((tid + 256) & 7) * 8;
    const short* Kbase = Kh + (long)(b * 512) * 1024 + h * 64;
    const _Float16* Vbase = Vt + (long)b * 524288 + (long)(h * 64) * 512;
    const _Float16* Gbase = (const _Float16*)G + ((long)((b * 16 + h) * 512 + qt * 64)) * 512;

    f32x4 oacc[4];
    #pragma unroll
    for (int r = 0; r < 4; ++r) oacc[r] = (f32x4){0.f, 0.f, 0.f, 0.f};
    float rs = 0.f;

    for (int kt = 0; kt < 8; ++kt) {
        __syncthreads();
        short8 k0 = *(const short8*)(Kbase + (long)(kt * 64 + sr0) * 1024 + sc0);
        short8 k1 = *(const short8*)(Kbase + (long)(kt * 64 + sr1) * 1024 + sc1);
        short8 v0 = *(const short8*)(Vbase + (long)sr0 * 512 + kt * 64 + sc0);
        short8 v1 = *(const short8*)(Vbase + (long)sr1 * 512 + kt * 64 + sc1);
        short8 g0 = *(const short8*)(Gbase + (long)sr0 * 512 + kt * 64 + sc0);
        short8 g1 = *(const short8*)(Gbase + (long)sr1 * 512 + kt * 64 + sc1);
        *(short8*)&Ks[sr0][sc0] = k0;
        *(short8*)&Ks[sr1][sc1] = k1;
        *(short8*)&Vs[sr0][sc0] = v0;
        *(short8*)&Vs[sr1][sc1] = v1;
        *(short8*)&Gs[sr0][sc0] = g0;
        *(short8*)&Gs[sr1][sc1] = g1;
        __syncthreads();

        f32x4 sc[4];
        #pragma unroll
        for (int nk = 0; nk < 4; ++nk) {
            bf16x8 bk0 = *(const bf16x8*)&Ks[nk * 16 + l16][quad * 8];
            bf16x8 bk1 = *(const bf16x8*)&Ks[nk * 16 + l16][32 + quad * 8];
            f32x4 s = (f32x4){0.f, 0.f, 0.f, 0.f};
            s = __builtin_amdgcn_mfma_f32_16x16x32_bf16(aq0, bk0, s, 0, 0, 0);
            s = __builtin_amdgcn_mfma_f32_16x16x32_bf16(aq1, bk1, s, 0, 0, 0);
            sc[nk] = s;
        }
        #pragma unroll
        for (int nk = 0; nk < 4; ++nk)
            #pragma unroll
            for (int r = 0; r < 4; ++r)
                Pbuf[wave][quad * 4 + r][nk * 16 + l16] = (_Float16)__expf(sc[nk][r] * 0.125f);
        f16x8 ep0 = *(const f16x8*)&Pbuf[wave][l16][quad * 8];
        f16x8 ep1 = *(const f16x8*)&Pbuf[wave][l16][32 + quad * 8];
        f16x8 gA = *(const f16x8*)&Gs[wave * 16 + l16][quad * 8];
        f16x8 gB = *(const f16x8*)&Gs[wave * 16 + l16][32 + quad * 8];
        f16x8 gp0 = ep0 * gA;
        f16x8 gp1 = ep1 * gB;
        float part = 0.f;
        #pragma unroll
        for (int j = 0; j < 8; ++j) part += (float)gp0[j] + (float)gp1[j];
        rs += part;
        #pragma unroll
        for (int n4 = 0; n4 < 4; ++n4) {
            f16x8 bv0 = *(const f16x8*)&Vs[n4 * 16 + l16][quad * 8];
            f16x8 bv1 = *(const f16x8*)&Vs[n4 * 16 + l16][32 + quad * 8];
            oacc[n4] = __builtin_amdgcn_mfma_f32_16x16x32_f16(gp0, bv0, oacc[n4], 0, 0, 0);
            oacc[n4] = __builtin_amdgcn_mfma_f32_16x16x32_f16(gp1, bv1, oacc[n4], 0, 0, 0);
        }
    }

    rs += __shfl_xor(rs, 16);
    rs += __shfl_xor(rs, 32);
    float li[4];
    #pragma unroll
    for (int r = 0; r < 4; ++r) li[r] = __shfl(rs, quad * 4 + r);

    #pragma unroll
    for (int n4 = 0; n4 < 4; ++n4)
        #pragma unroll
        for (int r = 0; r < 4; ++r) {
            float o = oacc[n4][r] / li[r];
            O[((long)(b * 512 + qrow + quad * 4 + r)) * 1024 + h * 64 + n4 * 16 + l16] = f2bf(o);
        }
}

// ---------- K4: Wo GEMM, 128x64 tiles, 512 blocks ----------
__global__ __launch_bounds__(256, 4)
void gemm_out2(const short* __restrict__ Hd, const short* __restrict__ wob,
               const float* __restrict__ bo, float* __restrict__ out) {
    __shared__ __align__(16) short As[4096];   // [128][32]
    __shared__ __align__(16) short Bs[2048];   // [64][32]
    const int tid = threadIdx.x;
    const int wave = tid >> 6, lane = tid & 63, quad = lane >> 4, l16 = lane & 15;
    const int m0 = blockIdx.y * 128, n0 = blockIdx.x * 64;
    const short* Ap = Hd + (long)m0 * 1024;
    const short* Bp = wob + (long)n0 * 1024;

    f32x4 acc[2][4];
    #pragma unroll
    for (int mg = 0; mg < 2; ++mg)
        #pragma unroll
        for (int ng = 0; ng < 4; ++ng) acc[mg][ng] = (f32x4){0.f, 0.f, 0.f, 0.f};

    const int r0 = tid >> 2, kk = (tid & 3) * 8;
    const short* ga0 = Ap + (long)r0 * 1024 + kk;
    const short* ga1 = Ap + (long)(64 + r0) * 1024 + kk;
    const short* gb0 = Bp + (long)r0 * 1024 + kk;
    short* la0 = As + wave * 512;
    short* la1 = As + 2048 + wave * 512;
    short* lb0 = Bs + wave * 512;

    const int mw = wave * 32;

    for (int k0 = 0; k0 < 1024; k0 += 32) {
        load_lds16(ga0 + k0, la0);
        load_lds16(ga1 + k0, la1);
        load_lds16(gb0 + k0, lb0);
        __syncthreads();
        bf16x8 a[2], bb[4];
        #pragma unroll
        for (int g = 0; g < 2; ++g)
            a[g] = *(const bf16x8*)&As[(mw + g * 16 + l16) * 32 + quad * 8];
        #pragma unroll
        for (int g = 0; g < 4; ++g)
            bb[g] = *(const bf16x8*)&Bs[(g * 16 + l16) * 32 + quad * 8];
        #pragma unroll
        for (int mg = 0; mg < 2; ++mg)
            #pragma unroll
            for (int ng = 0; ng < 4; ++ng)
                acc[mg][ng] = __builtin_amdgcn_mfma_f32_16x16x32_bf16(a[mg], bb[ng], acc[mg][ng], 0, 0, 0);
        __syncthreads();
    }

    #pragma unroll
    for (int mg = 0; mg < 2; ++mg)
        #pragma unroll
        for (int ng = 0; ng < 4; ++ng)
            #pragma unroll
            for (int r = 0; r < 4; ++r) {
                int row = m0 + mw + mg * 16 + quad * 4 + r;
                int col = n0 + ng * 16 + l16;
                out[(long)row * 1024 + col] = acc[mg][ng][r] + bo[col];
            }
}

// ---------- launch ----------
extern "C" void kernel_launch(void* const* d_in, const int* in_sizes, int n_in,
                              void* d_out, int out_size, void* d_ws, size_t ws_size,
                              hipStream_t stream) {
    const float* queries = (const float*)d_in[0];
    const float* keys    = (const float*)d_in[1];
    const float* values  = (const float*)d_in[2];
    const float* boxes   = (const float*)d_in[3];
    const float* bq = (const float*)d_in[5];
    const float* bk = (const float*)d_in[7];
    const float* bv = (const float*)d_in[9];
    const float* bo = (const float*)d_in[11];
    const float* Wg = (const float*)d_in[12];
    const float* bg = (const float*)d_in[13];

    char* ws = (char*)d_ws;
    short* qbf = (short*)(ws + 0);
    short* kbf = (short*)(ws + 8388608);
    short* vbf = (short*)(ws + 16777216);
    short* wqb = (short*)(ws + 25165824);    // wqb/wkb adjacent (z-stride 1048576 elems)
    short* wkb = (short*)(ws + 27262976);
    short* wvb = (short*)(ws + 29360128);
    short* wob = (short*)(ws + 31457280);
    short* Qh  = (short*)(ws + 33554432);    // Qh/Kh adjacent (z-stride 4194304 elems)
    _Float16* Vt = (_Float16*)(ws + 50331648);  // [b][1024 out][512 tok] f16
    short* Hd  = (short*)(ws + 58720256);    // hidden [4096][1024]
    __half* G  = (__half*)(ws + 67108864);   // g [b][h][512][512] f16, 67 MB
    _Float16* Wgh = (_Float16*)(ws + 33554432);  // overlaps Qh (dead before proj)

    convert_qkv<<<dim3(4096, 3), 256, 0, stream>>>(queries, keys, values, qbf, kbf, vbf);
    convert_w4<<<dim3(1024, 4), 256, 0, stream>>>((const float*)d_in[4], (const float*)d_in[6],
                                                  (const float*)d_in[8], (const float*)d_in[10],
                                                  wqb, wkb, wvb, wob);
    convert_f32_f16<<<4, 256, 0, stream>>>(Wg, Wgh, 1024);

    geom_kernel2<<<dim3(8, 512, 8), 256, 0, stream>>>(boxes, Wgh, bg, G);

    // all projections: 768 blocks (Q:256, K:256, V:256) = 3 blocks/CU, 128x128 tiles
    proj_all3<<<768, 256, 0, stream>>>(qbf, wqb, wvb, vbf, bq, bk, bv, Qh, Vt);

    flash_attn6<<<dim3(8, 16, 8), 256, 0, stream>>>(Qh, Qh + 4194304, Vt, G, Hd);

    // output projection -> f32 + bias, 512 blocks
    gemm_out2<<<dim3(16, 32), 256, 0, stream>>>(Hd, wob, bo, (float*)d_out);
}

// Round 2
// 269.460 us; speedup vs baseline: 1.0230x; 1.0090x over previous
//
#include <hip/hip_runtime.h>
#include <hip/hip_bf16.h>
#include <hip/hip_fp16.h>

// ---------- common types ----------
typedef __attribute__((ext_vector_type(8))) short bf16x8;      // 8 bf16 = 4 VGPR (MFMA A/B frag)
typedef __attribute__((ext_vector_type(8))) _Float16 f16x8;    // 8 f16  = 4 VGPR (MFMA A/B frag)
typedef __attribute__((ext_vector_type(4))) float f32x4;       // MFMA C/D frag
typedef __attribute__((ext_vector_type(8))) short short8;      // 16B chunk

__device__ __forceinline__ short f2bf(float x) {
    unsigned u = __builtin_bit_cast(unsigned, x);
    u += 0x7fffu + ((u >> 16) & 1u);          // RNE
    return (short)(u >> 16);
}

// async global->LDS, 16B per lane. lds dst must be wave-uniform base; HW scatters lane*16.
__device__ __forceinline__ void load_lds16(const void* g, void* l) {
    __builtin_amdgcn_global_load_lds((const __attribute__((address_space(1))) unsigned int*)g,
                                     (__attribute__((address_space(3))) unsigned int*)l, 16, 0, 0);
}

// ---------- K0: fused converts ----------
__global__ void convert_qkv(const float* __restrict__ q, const float* __restrict__ k,
                            const float* __restrict__ v, short* __restrict__ qo,
                            short* __restrict__ ko, short* __restrict__ vo) {
    int i = blockIdx.x * 256 + threadIdx.x;   // 1048576 float4 per tensor, grid (4096,3)
    const float* s = blockIdx.y == 0 ? q : blockIdx.y == 1 ? k : v;
    short* d = blockIdx.y == 0 ? qo : blockIdx.y == 1 ? ko : vo;
    float4 val = reinterpret_cast<const float4*>(s)[i];
    short4 o; o.x = f2bf(val.x); o.y = f2bf(val.y); o.z = f2bf(val.z); o.w = f2bf(val.w);
    reinterpret_cast<short4*>(d)[i] = o;
}

__global__ void convert_w4(const float* __restrict__ w0, const float* __restrict__ w1,
                           const float* __restrict__ w2, const float* __restrict__ w3,
                           short* __restrict__ o0, short* __restrict__ o1,
                           short* __restrict__ o2, short* __restrict__ o3) {
    int i = blockIdx.x * 256 + threadIdx.x;   // 262144 float4 per tensor, grid (1024,4)
    const float* s = blockIdx.y == 0 ? w0 : blockIdx.y == 1 ? w1 : blockIdx.y == 2 ? w2 : w3;
    short* d = blockIdx.y == 0 ? o0 : blockIdx.y == 1 ? o1 : blockIdx.y == 2 ? o2 : o3;
    float4 val = reinterpret_cast<const float4*>(s)[i];
    short4 o; o.x = f2bf(val.x); o.y = f2bf(val.y); o.z = f2bf(val.z); o.w = f2bf(val.w);
    reinterpret_cast<short4*>(d)[i] = o;
}

__global__ void convert_f32_f16(const float* __restrict__ src, _Float16* __restrict__ dst, int n) {
    int i = blockIdx.x * blockDim.x + threadIdx.x;
    if (i < n) dst[i] = (_Float16)src[i];
}

// ---------- K1: geometry bias via MFMA projection; stores g (f16, [b][h][n][m]) ----------
// Branchless pos: r = num/den per channel; log(clip(num/den)) == max(log num - log den, log clip)
// -> no IEEE divide, no 4-way exec-mask serialization.
__global__ void geom_kernel3(const float* __restrict__ boxes, const _Float16* __restrict__ Wgh,
                             const float* __restrict__ bg, __half* __restrict__ G) {
    const int tid = threadIdx.x;
    const int wave = tid >> 6, lane = tid & 63, quad = lane >> 4, l16 = lane & 15;
    const int m0 = blockIdx.x * 64;
    const int n = blockIdx.y;
    const int b = blockIdx.z;

    __shared__ __align__(16) _Float16 feat[4][16][72];
    __shared__ __align__(16) _Float16 gbuf[16][68];

    const int p = lane >> 2, c = lane & 3;
    const int m = m0 + wave * 16 + p;

    float4 bn = reinterpret_cast<const float4*>(boxes)[b * 512 + n];
    float4 bm = reinterpret_cast<const float4*>(boxes)[b * 512 + m];
    float cxn = (bn.x + bn.z) * 0.5f, cyn = (bn.y + bn.w) * 0.5f;
    float wn = bn.z - bn.x + 1.0f, hn = bn.w - bn.y + 1.0f;
    float cxm = (bm.x + bm.z) * 0.5f, cym = (bm.y + bm.w) * 0.5f;
    float wm = bm.z - bm.x + 1.0f, hm = bm.w - bm.y + 1.0f;

    // channel c: 0:|cx_n-cx_m|/wn  1:|cy_n-cy_m|/hn  2:wn/wm  3:hn/hm
    float num = (c == 0) ? fabsf(cxn - cxm) : (c == 1) ? fabsf(cyn - cym) : (c == 2) ? wn : hn;
    float den = (c == 0) ? wn : (c == 1) ? hn : (c == 2) ? wm : hm;
    float lr = __logf(num) - __logf(den);               // log(0) = -inf -> clamped below
    if (c < 2) lr = fmaxf(lr, -6.9077552790f);          // log(1e-3)
    float pos = lr * 100.0f;

    const float dm[8] = {1.0f, 0.42169651f, 0.17782794f, 0.07498942f,
                         0.03162278f, 0.01333521f, 0.00562341f, 0.00237137f};
    f16x8 sv8, cv8;
    #pragma unroll
    for (int f = 0; f < 8; ++f) {
        float th = pos * dm[f];
        sv8[f] = (_Float16)__sinf(th);
        cv8[f] = (_Float16)__cosf(th);
    }
    *(f16x8*)&feat[wave][p][c * 8]      = sv8;
    *(f16x8*)&feat[wave][p][32 + c * 8] = cv8;

    __syncthreads();

    f16x8 a0 = *(const f16x8*)&feat[wave][l16][quad * 8];
    f16x8 a1 = *(const f16x8*)&feat[wave][l16][32 + quad * 8];
    f16x8 b0 = *(const f16x8*)(Wgh + l16 * 64 + quad * 8);
    f16x8 b1 = *(const f16x8*)(Wgh + l16 * 64 + 32 + quad * 8);
    f32x4 acc = (f32x4){0.f, 0.f, 0.f, 0.f};
    acc = __builtin_amdgcn_mfma_f32_16x16x32_f16(a0, b0, acc, 0, 0, 0);
    acc = __builtin_amdgcn_mfma_f32_16x16x32_f16(a1, b1, acc, 0, 0, 0);

    float bgv = bg[l16];
    #pragma unroll
    for (int rr = 0; rr < 4; ++rr) {
        float g = fmaxf(acc[rr] + bgv, 1e-6f);        // relu + clip; store g itself
        gbuf[l16][wave * 16 + quad * 4 + rr] = (_Float16)g;
    }
    __syncthreads();

    const int h = tid >> 4, seg = tid & 15;
    ushort4 v = *(const ushort4*)&gbuf[h][seg * 4];
    *(ushort4*)&G[((long)((b * 16 + h) * 512 + n)) * 512 + m0 + seg * 4] = v;
}

// ---------- K2: ALL projections, 128x128 tiles, 3-buffer 2-ahead prefetch ----------
// T3/T4 recipe: counted vmcnt(4) (never 0 in main loop), ONE raw barrier per K-step.
// Per step t: [vmcnt(4)] [barrier] [stage tile t+2 -> buf (t+2)%3] [ds_read buf t%3] [16 MFMA]
#define PROJ_COMP(BC)                                                                  \
    {                                                                                  \
        bf16x8 a_[4], bb_[4];                                                          \
        _Pragma("unroll")                                                              \
        for (int g = 0; g < 4; ++g)                                                    \
            a_[g] = *(const bf16x8*)&As[BC][(wr * 64 + g * 16 + l16) * 32 + quad * 8]; \
        _Pragma("unroll")                                                              \
        for (int g = 0; g < 4; ++g)                                                    \
            bb_[g] = *(const bf16x8*)&Bs[BC][(wc * 64 + g * 16 + l16) * 32 + quad * 8];\
        _Pragma("unroll")                                                              \
        for (int mg = 0; mg < 4; ++mg)                                                 \
            _Pragma("unroll")                                                          \
            for (int ng = 0; ng < 4; ++ng)                                             \
                acc[mg][ng] = __builtin_amdgcn_mfma_f32_16x16x32_bf16(a_[mg], bb_[ng], acc[mg][ng], 0, 0, 0); \
    }

#define PROJ_STEP(T, BC, BS)                                                           \
    {                                                                                  \
        asm volatile("s_waitcnt vmcnt(4)" ::: "memory");                               \
        __builtin_amdgcn_s_barrier();                                                  \
        const int k1_ = ((T) + 2) * 32;                                                \
        load_lds16(ga0 + k1_, &As[BS][wb]);                                            \
        load_lds16(ga1 + k1_, &As[BS][2048 + wb]);                                     \
        load_lds16(gb0 + k1_, &Bs[BS][wb]);                                            \
        load_lds16(gb1 + k1_, &Bs[BS][2048 + wb]);                                     \
        PROJ_COMP(BC)                                                                  \
    }

__global__ __launch_bounds__(256, 3)
void proj_all4(const short* __restrict__ qkbf, const short* __restrict__ wqkb,
               const short* __restrict__ wvb, const short* __restrict__ vbf,
               const float* __restrict__ bq, const float* __restrict__ bk,
               const float* __restrict__ bv,
               short* __restrict__ QKh, _Float16* __restrict__ Vt) {
    __shared__ __align__(16) short As[3][4096];   // 3 x [128][32]
    __shared__ __align__(16) short Bs[3][4096];
    const int tid = threadIdx.x;
    const int wave = tid >> 6, lane = tid & 63, quad = lane >> 4, l16 = lane & 15;
    const int bid = blockIdx.x;

    const short *Ap, *Bp;
    int m0, n0, z = 0;
    bool isV = bid >= 512;
    if (!isV) {
        z = bid >> 8;
        int t = bid & 255;
        n0 = (t & 7) * 128; m0 = (t >> 3) * 128;
        Ap = qkbf + (long)z * 4194304 + (long)m0 * 1024;
        Bp = wqkb + (long)z * 1048576 + (long)n0 * 1024;
    } else {
        int t = bid - 512;
        n0 = (t & 31) * 128; m0 = (t >> 5) * 128;
        Ap = wvb + (long)m0 * 1024;
        Bp = vbf + (long)n0 * 1024;
    }

    f32x4 acc[4][4];
    #pragma unroll
    for (int mg = 0; mg < 4; ++mg)
        #pragma unroll
        for (int ng = 0; ng < 4; ++ng) acc[mg][ng] = (f32x4){0.f, 0.f, 0.f, 0.f};

    const int r0 = tid >> 2, kk = (tid & 3) * 8;
    const short* ga0 = Ap + (long)r0 * 1024 + kk;
    const short* ga1 = Ap + (long)(64 + r0) * 1024 + kk;
    const short* gb0 = Bp + (long)r0 * 1024 + kk;
    const short* gb1 = Bp + (long)(64 + r0) * 1024 + kk;
    const int wb = wave * 512;
    const int wr = wave >> 1, wc = wave & 1;   // 2x2 wave grid, 64x64 per wave

    // prologue: stage tiles 0 and 1 (tile-0 loads issued first => oldest for vmcnt)
    load_lds16(ga0, &As[0][wb]);
    load_lds16(ga1, &As[0][2048 + wb]);
    load_lds16(gb0, &Bs[0][wb]);
    load_lds16(gb1, &Bs[0][2048 + wb]);
    load_lds16(ga0 + 32, &As[1][wb]);
    load_lds16(ga1 + 32, &As[1][2048 + wb]);
    load_lds16(gb0 + 32, &Bs[1][wb]);
    load_lds16(gb1 + 32, &Bs[1][2048 + wb]);

    for (int tb = 0; tb < 30; tb += 3) {   // steps 0..29, staging tiles 2..31
        PROJ_STEP(tb,     0, 2)
        PROJ_STEP(tb + 1, 1, 0)
        PROJ_STEP(tb + 2, 2, 1)
    }
    // tail: t=30 (buf 0), t=31 (buf 1), no staging
    asm volatile("s_waitcnt vmcnt(4)" ::: "memory");
    __builtin_amdgcn_s_barrier();
    PROJ_COMP(0)
    asm volatile("s_waitcnt vmcnt(0)" ::: "memory");
    __builtin_amdgcn_s_barrier();
    PROJ_COMP(1)

    #pragma unroll
    for (int mg = 0; mg < 4; ++mg)
        #pragma unroll
        for (int ng = 0; ng < 4; ++ng)
            #pragma unroll
            for (int r = 0; r < 4; ++r) {
                int row = m0 + wr * 64 + mg * 16 + quad * 4 + r;
                int col = n0 + wc * 64 + ng * 16 + l16;
                if (!isV) {
                    float v = acc[mg][ng][r] + (z ? bk[col] : bq[col]);
                    QKh[(long)z * 4194304 + (long)row * 1024 + col] = f2bf(v);
                } else {
                    float v = acc[mg][ng][r] + bv[row];
                    int bcol = col >> 9, lc = col & 511;    // token -> (batch, local)
                    Vt[(long)bcol * 524288 + (long)row * 512 + lc] = (_Float16)v;
                }
            }
}

// ---------- K3: flash attention, m97-style cooperative LDS staging ----------
__global__ __launch_bounds__(256, 4)
void flash_attn6(const short* __restrict__ Q, const short* __restrict__ Kh,
                 const _Float16* __restrict__ Vt, const __half* __restrict__ G,
                 short* __restrict__ O) {
    const int tid = threadIdx.x;
    const int wave = tid >> 6, lane = tid & 63, quad = lane >> 4, l16 = lane & 15;
    const int qt = blockIdx.x, h = blockIdx.y, b = blockIdx.z;

    __shared__ __align__(16) short    Ks[64][72];        // [kv][d]
    __shared__ __align__(16) _Float16 Vs[64][72];        // [d][kv]
    __shared__ __align__(16) _Float16 Gs[64][72];        // [q][kv]
    __shared__ __align__(16) _Float16 Pbuf[4][16][72];   // per-wave private

    const int qrow = qt * 64 + wave * 16;
    const long qoff = ((long)(b * 512 + qrow + l16)) * 1024 + h * 64 + quad * 8;
    bf16x8 aq0 = *(const bf16x8*)(Q + qoff);
    bf16x8 aq1 = *(const bf16x8*)(Q + qoff + 32);

    const int sr0 = tid >> 3,         sc0 = (tid & 7) * 8;
    const int sr1 = (tid + 256) >> 3, sc1 = ((tid + 256) & 7) * 8;
    const short* Kbase = Kh + (long)(b * 512) * 1024 + h * 64;
    const _Float16* Vbase = Vt + (long)b * 524288 + (long)(h * 64) * 512;
    const _Float16* Gbase = (const _Float16*)G + ((long)((b * 16 + h) * 512 + qt * 64)) * 512;

    f32x4 oacc[4];
    #pragma unroll
    for (int r = 0; r < 4; ++r) oacc[r] = (f32x4){0.f, 0.f, 0.f, 0.f};
    float rs = 0.f;

    for (int kt = 0; kt < 8; ++kt) {
        __syncthreads();
        short8 k0 = *(const short8*)(Kbase + (long)(kt * 64 + sr0) * 1024 + sc0);
        short8 k1 = *(const short8*)(Kbase + (long)(kt * 64 + sr1) * 1024 + sc1);
        short8 v0 = *(const short8*)(Vbase + (long)sr0 * 512 + kt * 64 + sc0);
        short8 v1 = *(const short8*)(Vbase + (long)sr1 * 512 + kt * 64 + sc1);
        short8 g0 = *(const short8*)(Gbase + (long)sr0 * 512 + kt * 64 + sc0);
        short8 g1 = *(const short8*)(Gbase + (long)sr1 * 512 + kt * 64 + sc1);
        *(short8*)&Ks[sr0][sc0] = k0;
        *(short8*)&Ks[sr1][sc1] = k1;
        *(short8*)&Vs[sr0][sc0] = v0;
        *(short8*)&Vs[sr1][sc1] = v1;
        *(short8*)&Gs[sr0][sc0] = g0;
        *(short8*)&Gs[sr1][sc1] = g1;
        __syncthreads();

        f32x4 sc[4];
        #pragma unroll
        for (int nk = 0; nk < 4; ++nk) {
            bf16x8 bk0 = *(const bf16x8*)&Ks[nk * 16 + l16][quad * 8];
            bf16x8 bk1 = *(const bf16x8*)&Ks[nk * 16 + l16][32 + quad * 8];
            f32x4 s = (f32x4){0.f, 0.f, 0.f, 0.f};
            s = __builtin_amdgcn_mfma_f32_16x16x32_bf16(aq0, bk0, s, 0, 0, 0);
            s = __builtin_amdgcn_mfma_f32_16x16x32_bf16(aq1, bk1, s, 0, 0, 0);
            sc[nk] = s;
        }
        #pragma unroll
        for (int nk = 0; nk < 4; ++nk)
            #pragma unroll
            for (int r = 0; r < 4; ++r)
                Pbuf[wave][quad * 4 + r][nk * 16 + l16] = (_Float16)__expf(sc[nk][r] * 0.125f);
        f16x8 ep0 = *(const f16x8*)&Pbuf[wave][l16][quad * 8];
        f16x8 ep1 = *(const f16x8*)&Pbuf[wave][l16][32 + quad * 8];
        f16x8 gA = *(const f16x8*)&Gs[wave * 16 + l16][quad * 8];
        f16x8 gB = *(const f16x8*)&Gs[wave * 16 + l16][32 + quad * 8];
        f16x8 gp0 = ep0 * gA;
        f16x8 gp1 = ep1 * gB;
        float part = 0.f;
        #pragma unroll
        for (int j = 0; j < 8; ++j) part += (float)gp0[j] + (float)gp1[j];
        rs += part;
        #pragma unroll
        for (int n4 = 0; n4 < 4; ++n4) {
            f16x8 bv0 = *(const f16x8*)&Vs[n4 * 16 + l16][quad * 8];
            f16x8 bv1 = *(const f16x8*)&Vs[n4 * 16 + l16][32 + quad * 8];
            oacc[n4] = __builtin_amdgcn_mfma_f32_16x16x32_f16(gp0, bv0, oacc[n4], 0, 0, 0);
            oacc[n4] = __builtin_amdgcn_mfma_f32_16x16x32_f16(gp1, bv1, oacc[n4], 0, 0, 0);
        }
    }

    rs += __shfl_xor(rs, 16);
    rs += __shfl_xor(rs, 32);
    float li[4];
    #pragma unroll
    for (int r = 0; r < 4; ++r) li[r] = __shfl(rs, quad * 4 + r);

    #pragma unroll
    for (int n4 = 0; n4 < 4; ++n4)
        #pragma unroll
        for (int r = 0; r < 4; ++r) {
            float o = oacc[n4][r] / li[r];
            O[((long)(b * 512 + qrow + quad * 4 + r)) * 1024 + h * 64 + n4 * 16 + l16] = f2bf(o);
        }
}

// ---------- K4: Wo GEMM, 128x64 tiles, 3-buffer 2-ahead prefetch ----------
#define GOUT_COMP(BC)                                                                  \
    {                                                                                  \
        bf16x8 a_[2], bb_[4];                                                          \
        _Pragma("unroll")                                                              \
        for (int g = 0; g < 2; ++g)                                                    \
            a_[g] = *(const bf16x8*)&As[BC][(mw + g * 16 + l16) * 32 + quad * 8];      \
        _Pragma("unroll")                                                              \
        for (int g = 0; g < 4; ++g)                                                    \
            bb_[g] = *(const bf16x8*)&Bs[BC][(g * 16 + l16) * 32 + quad * 8];          \
        _Pragma("unroll")                                                              \
        for (int mg = 0; mg < 2; ++mg)                                                 \
            _Pragma("unroll")                                                          \
            for (int ng = 0; ng < 4; ++ng)                                             \
                acc[mg][ng] = __builtin_amdgcn_mfma_f32_16x16x32_bf16(a_[mg], bb_[ng], acc[mg][ng], 0, 0, 0); \
    }

#define GOUT_STEP(T, BC, BS)                                                           \
    {                                                                                  \
        asm volatile("s_waitcnt vmcnt(3)" ::: "memory");                               \
        __builtin_amdgcn_s_barrier();                                                  \
        const int k1_ = ((T) + 2) * 32;                                                \
        load_lds16(ga0 + k1_, &As[BS][wb]);                                            \
        load_lds16(ga1 + k1_, &As[BS][2048 + wb]);                                     \
        load_lds16(gb0 + k1_, &Bs[BS][wb]);                                            \
        GOUT_COMP(BC)                                                                  \
    }

__global__ __launch_bounds__(256, 4)
void gemm_out3(const short* __restrict__ Hd, const short* __restrict__ wob,
               const float* __restrict__ bo, float* __restrict__ out) {
    __shared__ __align__(16) short As[3][4096];   // 3 x [128][32]
    __shared__ __align__(16) short Bs[3][2048];   // 3 x [64][32]
    const int tid = threadIdx.x;
    const int wave = tid >> 6, lane = tid & 63, quad = lane >> 4, l16 = lane & 15;
    const int m0 = blockIdx.y * 128, n0 = blockIdx.x * 64;
    const short* Ap = Hd + (long)m0 * 1024;
    const short* Bp = wob + (long)n0 * 1024;

    f32x4 acc[2][4];
    #pragma unroll
    for (int mg = 0; mg < 2; ++mg)
        #pragma unroll
        for (int ng = 0; ng < 4; ++ng) acc[mg][ng] = (f32x4){0.f, 0.f, 0.f, 0.f};

    const int r0 = tid >> 2, kk = (tid & 3) * 8;
    const short* ga0 = Ap + (long)r0 * 1024 + kk;
    const short* ga1 = Ap + (long)(64 + r0) * 1024 + kk;
    const short* gb0 = Bp + (long)r0 * 1024 + kk;
    const int wb = wave * 512;
    const int mw = wave * 32;

    // prologue: stage tiles 0 and 1
    load_lds16(ga0, &As[0][wb]);
    load_lds16(ga1, &As[0][2048 + wb]);
    load_lds16(gb0, &Bs[0][wb]);
    load_lds16(ga0 + 32, &As[1][wb]);
    load_lds16(ga1 + 32, &As[1][2048 + wb]);
    load_lds16(gb0 + 32, &Bs[1][wb]);

    for (int tb = 0; tb < 30; tb += 3) {
        GOUT_STEP(tb,     0, 2)
        GOUT_STEP(tb + 1, 1, 0)
        GOUT_STEP(tb + 2, 2, 1)
    }
    asm volatile("s_waitcnt vmcnt(3)" ::: "memory");
    __builtin_amdgcn_s_barrier();
    GOUT_COMP(0)
    asm volatile("s_waitcnt vmcnt(0)" ::: "memory");
    __builtin_amdgcn_s_barrier();
    GOUT_COMP(1)

    #pragma unroll
    for (int mg = 0; mg < 2; ++mg)
        #pragma unroll
        for (int ng = 0; ng < 4; ++ng)
            #pragma unroll
            for (int r = 0; r < 4; ++r) {
                int row = m0 + mw + mg * 16 + quad * 4 + r;
                int col = n0 + ng * 16 + l16;
                out[(long)row * 1024 + col] = acc[mg][ng][r] + bo[col];
            }
}

// ---------- launch ----------
extern "C" void kernel_launch(void* const* d_in, const int* in_sizes, int n_in,
                              void* d_out, int out_size, void* d_ws, size_t ws_size,
                              hipStream_t stream) {
    const float* queries = (const float*)d_in[0];
    const float* keys    = (const float*)d_in[1];
    const float* values  = (const float*)d_in[2];
    const float* boxes   = (const float*)d_in[3];
    const float* bq = (const float*)d_in[5];
    const float* bk = (const float*)d_in[7];
    const float* bv = (const float*)d_in[9];
    const float* bo = (const float*)d_in[11];
    const float* Wg = (const float*)d_in[12];
    const float* bg = (const float*)d_in[13];

    char* ws = (char*)d_ws;
    short* qbf = (short*)(ws + 0);
    short* kbf = (short*)(ws + 8388608);
    short* vbf = (short*)(ws + 16777216);
    short* wqb = (short*)(ws + 25165824);    // wqb/wkb adjacent (z-stride 1048576 elems)
    short* wkb = (short*)(ws + 27262976);
    short* wvb = (short*)(ws + 29360128);
    short* wob = (short*)(ws + 31457280);
    short* Qh  = (short*)(ws + 33554432);    // Qh/Kh adjacent (z-stride 4194304 elems)
    _Float16* Vt = (_Float16*)(ws + 50331648);  // [b][1024 out][512 tok] f16
    short* Hd  = (short*)(ws + 58720256);    // hidden [4096][1024]
    __half* G  = (__half*)(ws + 67108864);   // g [b][h][512][512] f16, 67 MB
    _Float16* Wgh = (_Float16*)(ws + 33554432);  // overlaps Qh (dead before proj)

    convert_qkv<<<dim3(4096, 3), 256, 0, stream>>>(queries, keys, values, qbf, kbf, vbf);
    convert_w4<<<dim3(1024, 4), 256, 0, stream>>>((const float*)d_in[4], (const float*)d_in[6],
                                                  (const float*)d_in[8], (const float*)d_in[10],
                                                  wqb, wkb, wvb, wob);
    convert_f32_f16<<<4, 256, 0, stream>>>(Wg, Wgh, 1024);

    geom_kernel3<<<dim3(8, 512, 8), 256, 0, stream>>>(boxes, Wgh, bg, G);

    // all projections: 768 blocks (Q:256, K:256, V:256), 128x128 tiles, 3-deep prefetch
    proj_all4<<<768, 256, 0, stream>>>(qbf, wqb, wvb, vbf, bq, bk, bv, Qh, Vt);

    flash_attn6<<<dim3(8, 16, 8), 256, 0, stream>>>(Qh, Qh + 4194304, Vt, G, Hd);

    // output projection -> f32 + bias, 512 blocks, 3-deep prefetch
    gemm_out3<<<dim3(16, 32), 256, 0, stream>>>(Hd, wob, bo, (float*)d_out);
}

// Round 4
// 258.989 us; speedup vs baseline: 1.0643x; 1.0404x over previous
//
#include <hip/hip_runtime.h>
#include <hip/hip_bf16.h>
#include <hip/hip_fp16.h>

// ---------- common types ----------
typedef __attribute__((ext_vector_type(8))) short bf16x8;      // 8 bf16 = 4 VGPR (MFMA A/B frag)
typedef __attribute__((ext_vector_type(8))) _Float16 f16x8;    // 8 f16  = 4 VGPR (MFMA A/B frag)
typedef __attribute__((ext_vector_type(4))) float f32x4;       // MFMA C/D frag
typedef __attribute__((ext_vector_type(8))) short short8;      // 16B chunk

__device__ __forceinline__ short f2bf(float x) {
    unsigned u = __builtin_bit_cast(unsigned, x);
    u += 0x7fffu + ((u >> 16) & 1u);          // RNE
    return (short)(u >> 16);
}

// async global->LDS, 16B per lane. lds dst must be wave-uniform base; HW scatters lane*16.
__device__ __forceinline__ void load_lds16(const void* g, void* l) {
    __builtin_amdgcn_global_load_lds((const __attribute__((address_space(1))) unsigned int*)g,
                                     (__attribute__((address_space(3))) unsigned int*)l, 16, 0, 0);
}

// ---------- K0: fused converts ----------
__global__ void convert_qkv(const float* __restrict__ q, const float* __restrict__ k,
                            const float* __restrict__ v, short* __restrict__ qo,
                            short* __restrict__ ko, short* __restrict__ vo) {
    int i = blockIdx.x * 256 + threadIdx.x;   // 1048576 float4 per tensor, grid (4096,3)
    const float* s = blockIdx.y == 0 ? q : blockIdx.y == 1 ? k : v;
    short* d = blockIdx.y == 0 ? qo : blockIdx.y == 1 ? ko : vo;
    float4 val = reinterpret_cast<const float4*>(s)[i];
    short4 o; o.x = f2bf(val.x); o.y = f2bf(val.y); o.z = f2bf(val.z); o.w = f2bf(val.w);
    reinterpret_cast<short4*>(d)[i] = o;
}

__global__ void convert_w4(const float* __restrict__ w0, const float* __restrict__ w1,
                           const float* __restrict__ w2, const float* __restrict__ w3,
                           short* __restrict__ o0, short* __restrict__ o1,
                           short* __restrict__ o2, short* __restrict__ o3) {
    int i = blockIdx.x * 256 + threadIdx.x;   // 262144 float4 per tensor, grid (1024,4)
    const float* s = blockIdx.y == 0 ? w0 : blockIdx.y == 1 ? w1 : blockIdx.y == 2 ? w2 : w3;
    short* d = blockIdx.y == 0 ? o0 : blockIdx.y == 1 ? o1 : blockIdx.y == 2 ? o2 : o3;
    float4 val = reinterpret_cast<const float4*>(s)[i];
    short4 o; o.x = f2bf(val.x); o.y = f2bf(val.y); o.z = f2bf(val.z); o.w = f2bf(val.w);
    reinterpret_cast<short4*>(d)[i] = o;
}

__global__ void convert_f32_f16(const float* __restrict__ src, _Float16* __restrict__ dst, int n) {
    int i = blockIdx.x * blockDim.x + threadIdx.x;
    if (i < n) dst[i] = (_Float16)src[i];
}

// ---------- K1: geometry bias. 64 m x 8 n per block (grid 4096, 8x fatter blocks) ----------
// Per-thread m-side quantities + log(wm)/log(hm) + Wg fragments hoisted out of the n-loop.
// Per n: 1 pairwise log + 8 sin + 8 cos + selects. Channels 2/3 use separable log-subtraction.
__global__ __launch_bounds__(256)
void geom_kernel4(const float* __restrict__ boxes, const _Float16* __restrict__ Wgh,
                  const float* __restrict__ bg, __half* __restrict__ G) {
    const int tid = threadIdx.x;
    const int wave = tid >> 6, lane = tid & 63, quad = lane >> 4, l16 = lane & 15;
    const int m0 = blockIdx.x * 64;
    const int n0 = blockIdx.y * 8;
    const int b = blockIdx.z;

    __shared__ __align__(16) _Float16 feat[4][16][72];
    __shared__ __align__(16) _Float16 gbuf[16][68];

    const int p = lane >> 2, c = lane & 3;
    const int m = m0 + wave * 16 + p;

    // m-side (per-thread, hoisted)
    float4 bm = reinterpret_cast<const float4*>(boxes)[b * 512 + m];
    float cxm = (bm.x + bm.z) * 0.5f, cym = (bm.y + bm.w) * 0.5f;
    float wm = bm.z - bm.x + 1.0f, hm = bm.w - bm.y + 1.0f;
    float lwm = __logf(wm), lhm = __logf(hm);

    // Wg fragments (constant across n) + bias
    f16x8 wb0 = *(const f16x8*)(Wgh + l16 * 64 + quad * 8);
    f16x8 wb1 = *(const f16x8*)(Wgh + l16 * 64 + 32 + quad * 8);
    float bgv = bg[l16];

    const float dm[8] = {1.0f, 0.42169651f, 0.17782794f, 0.07498942f,
                         0.03162278f, 0.01333521f, 0.00562341f, 0.00237137f};
    const int h = tid >> 4, seg = tid & 15;

    for (int ni = 0; ni < 8; ++ni) {
        const int n = n0 + ni;
        float4 bn = reinterpret_cast<const float4*>(boxes)[b * 512 + n];   // uniform
        float cxn = (bn.x + bn.z) * 0.5f, cyn = (bn.y + bn.w) * 0.5f;
        float wn = bn.z - bn.x + 1.0f, hn = bn.w - bn.y + 1.0f;
        float lwn = __logf(wn), lhn = __logf(hn);

        // channel c: 0:|cxn-cxm|/wn  1:|cyn-cym|/hn  2:wn/wm  3:hn/hm
        float numa = (c == 1) ? fabsf(cyn - cym) : fabsf(cxn - cxm);
        float pl = fmaxf(__logf(numa) - ((c == 1) ? lhn : lwn), -6.9077552790f);  // log(1e-3)
        float sl = (c == 3) ? (lhn - lhm) : (lwn - lwm);
        float pos = ((c < 2) ? pl : sl) * 100.0f;

        f16x8 sv8, cv8;
        #pragma unroll
        for (int f = 0; f < 8; ++f) {
            float th = pos * dm[f];
            sv8[f] = (_Float16)__sinf(th);
            cv8[f] = (_Float16)__cosf(th);
        }
        *(f16x8*)&feat[wave][p][c * 8]      = sv8;
        *(f16x8*)&feat[wave][p][32 + c * 8] = cv8;

        __syncthreads();

        f16x8 a0 = *(const f16x8*)&feat[wave][l16][quad * 8];
        f16x8 a1 = *(const f16x8*)&feat[wave][l16][32 + quad * 8];
        f32x4 acc = (f32x4){0.f, 0.f, 0.f, 0.f};
        acc = __builtin_amdgcn_mfma_f32_16x16x32_f16(a0, wb0, acc, 0, 0, 0);
        acc = __builtin_amdgcn_mfma_f32_16x16x32_f16(a1, wb1, acc, 0, 0, 0);

        #pragma unroll
        for (int rr = 0; rr < 4; ++rr) {
            float g = fmaxf(acc[rr] + bgv, 1e-6f);        // relu + clip; store g itself
            gbuf[l16][wave * 16 + quad * 4 + rr] = (_Float16)g;
        }
        __syncthreads();

        ushort4 v = *(const ushort4*)&gbuf[h][seg * 4];
        *(ushort4*)&G[((long)((b * 16 + h) * 512 + n)) * 512 + m0 + seg * 4] = v;
    }
}

// ---------- K2: ALL projections, 128x128 tiles, 3-buffer 2-ahead prefetch + XCD swizzle ----------
#define PROJ_COMP(BC)                                                                  \
    {                                                                                  \
        bf16x8 a_[4], bb_[4];                                                          \
        _Pragma("unroll")                                                              \
        for (int g = 0; g < 4; ++g)                                                    \
            a_[g] = *(const bf16x8*)&As[BC][(wr * 64 + g * 16 + l16) * 32 + quad * 8]; \
        _Pragma("unroll")                                                              \
        for (int g = 0; g < 4; ++g)                                                    \
            bb_[g] = *(const bf16x8*)&Bs[BC][(wc * 64 + g * 16 + l16) * 32 + quad * 8];\
        _Pragma("unroll")                                                              \
        for (int mg = 0; mg < 4; ++mg)                                                 \
            _Pragma("unroll")                                                          \
            for (int ng = 0; ng < 4; ++ng)                                             \
                acc[mg][ng] = __builtin_amdgcn_mfma_f32_16x16x32_bf16(a_[mg], bb_[ng], acc[mg][ng], 0, 0, 0); \
    }

#define PROJ_STEP(T, BC, BS)                                                           \
    {                                                                                  \
        asm volatile("s_waitcnt vmcnt(4)" ::: "memory");                               \
        __builtin_amdgcn_s_barrier();                                                  \
        const int k1_ = ((T) + 2) * 32;                                                \
        load_lds16(ga0 + k1_, &As[BS][wb]);                                            \
        load_lds16(ga1 + k1_, &As[BS][2048 + wb]);                                     \
        load_lds16(gb0 + k1_, &Bs[BS][wb]);                                            \
        load_lds16(gb1 + k1_, &Bs[BS][2048 + wb]);                                     \
        PROJ_COMP(BC)                                                                  \
    }

__global__ __launch_bounds__(256, 3)
void proj_all5(const short* __restrict__ qkbf, const short* __restrict__ wqkb,
               const short* __restrict__ wvb, const short* __restrict__ vbf,
               const float* __restrict__ bq, const float* __restrict__ bk,
               const float* __restrict__ bv,
               short* __restrict__ QKh, _Float16* __restrict__ Vt) {
    __shared__ __align__(16) short As[3][4096];   // 3 x [128][32]
    __shared__ __align__(16) short Bs[3][4096];
    const int tid = threadIdx.x;
    const int wave = tid >> 6, lane = tid & 63, quad = lane >> 4, l16 = lane & 15;
    // T1 XCD swizzle: 768 blocks = 8 XCDs x 96-chunk (bijective). Panel-sharing
    // blocks (consecutive logical ids) land on one XCD -> A/B panels L2-hit.
    const int bid = (blockIdx.x & 7) * 96 + (blockIdx.x >> 3);

    const short *Ap, *Bp;
    int m0, n0, z = 0;
    bool isV = bid >= 512;
    if (!isV) {
        z = bid >> 8;
        int t = bid & 255;
        n0 = (t & 7) * 128; m0 = (t >> 3) * 128;      // 8 consecutive share token panel
        Ap = qkbf + (long)z * 4194304 + (long)m0 * 1024;
        Bp = wqkb + (long)z * 1048576 + (long)n0 * 1024;
    } else {
        int t = bid - 512;
        m0 = (t & 7) * 128; n0 = (t >> 3) * 128;      // 8 consecutive share token panel (vbf)
        Ap = wvb + (long)m0 * 1024;
        Bp = vbf + (long)n0 * 1024;
    }

    f32x4 acc[4][4];
    #pragma unroll
    for (int mg = 0; mg < 4; ++mg)
        #pragma unroll
        for (int ng = 0; ng < 4; ++ng) acc[mg][ng] = (f32x4){0.f, 0.f, 0.f, 0.f};

    const int r0 = tid >> 2, kk = (tid & 3) * 8;
    const short* ga0 = Ap + (long)r0 * 1024 + kk;
    const short* ga1 = Ap + (long)(64 + r0) * 1024 + kk;
    const short* gb0 = Bp + (long)r0 * 1024 + kk;
    const short* gb1 = Bp + (long)(64 + r0) * 1024 + kk;
    const int wb = wave * 512;
    const int wr = wave >> 1, wc = wave & 1;   // 2x2 wave grid, 64x64 per wave

    // prologue: stage tiles 0 and 1 (tile-0 loads issued first => oldest for vmcnt)
    load_lds16(ga0, &As[0][wb]);
    load_lds16(ga1, &As[0][2048 + wb]);
    load_lds16(gb0, &Bs[0][wb]);
    load_lds16(gb1, &Bs[0][2048 + wb]);
    load_lds16(ga0 + 32, &As[1][wb]);
    load_lds16(ga1 + 32, &As[1][2048 + wb]);
    load_lds16(gb0 + 32, &Bs[1][wb]);
    load_lds16(gb1 + 32, &Bs[1][2048 + wb]);

    for (int tb = 0; tb < 30; tb += 3) {   // steps 0..29, staging tiles 2..31
        PROJ_STEP(tb,     0, 2)
        PROJ_STEP(tb + 1, 1, 0)
        PROJ_STEP(tb + 2, 2, 1)
    }
    // tail: t=30 (buf 0), t=31 (buf 1), no staging
    asm volatile("s_waitcnt vmcnt(4)" ::: "memory");
    __builtin_amdgcn_s_barrier();
    PROJ_COMP(0)
    asm volatile("s_waitcnt vmcnt(0)" ::: "memory");
    __builtin_amdgcn_s_barrier();
    PROJ_COMP(1)

    #pragma unroll
    for (int mg = 0; mg < 4; ++mg)
        #pragma unroll
        for (int ng = 0; ng < 4; ++ng)
            #pragma unroll
            for (int r = 0; r < 4; ++r) {
                int row = m0 + wr * 64 + mg * 16 + quad * 4 + r;
                int col = n0 + wc * 64 + ng * 16 + l16;
                if (!isV) {
                    float v = acc[mg][ng][r] + (z ? bk[col] : bq[col]);
                    QKh[(long)z * 4194304 + (long)row * 1024 + col] = f2bf(v);
                } else {
                    float v = acc[mg][ng][r] + bv[row];
                    int bcol = col >> 9, lc = col & 511;    // token -> (batch, local)
                    Vt[(long)bcol * 524288 + (long)row * 512 + lc] = (_Float16)v;
                }
            }
}

// ---------- K3: flash attention, m97-style cooperative LDS staging ----------
__global__ __launch_bounds__(256, 4)
void flash_attn6(const short* __restrict__ Q, const short* __restrict__ Kh,
                 const _Float16* __restrict__ Vt, const __half* __restrict__ G,
                 short* __restrict__ O) {
    const int tid = threadIdx.x;
    const int wave = tid >> 6, lane = tid & 63, quad = lane >> 4, l16 = lane & 15;
    const int qt = blockIdx.x, h = blockIdx.y, b = blockIdx.z;

    __shared__ __align__(16) short    Ks[64][72];        // [kv][d]
    __shared__ __align__(16) _Float16 Vs[64][72];        // [d][kv]
    __shared__ __align__(16) _Float16 Gs[64][72];        // [q][kv]
    __shared__ __align__(16) _Float16 Pbuf[4][16][72];   // per-wave private

    const int qrow = qt * 64 + wave * 16;
    const long qoff = ((long)(b * 512 + qrow + l16)) * 1024 + h * 64 + quad * 8;
    bf16x8 aq0 = *(const bf16x8*)(Q + qoff);
    bf16x8 aq1 = *(const bf16x8*)(Q + qoff + 32);

    const int sr0 = tid >> 3,         sc0 = (tid & 7) * 8;
    const int sr1 = (tid + 256) >> 3, sc1 = ((tid + 256) & 7) * 8;
    const short* Kbase = Kh + (long)(b * 512) * 1024 + h * 64;
    const _Float16* Vbase = Vt + (long)b * 524288 + (long)(h * 64) * 512;
    const _Float16* Gbase = (const _Float16*)G + ((long)((b * 16 + h) * 512 + qt * 64)) * 512;

    f32x4 oacc[4];
    #pragma unroll
    for (int r = 0; r < 4; ++r) oacc[r] = (f32x4){0.f, 0.f, 0.f, 0.f};
    float rs = 0.f;

    for (int kt = 0; kt < 8; ++kt) {
        __syncthreads();
        short8 k0 = *(const short8*)(Kbase + (long)(kt * 64 + sr0) * 1024 + sc0);
        short8 k1 = *(const short8*)(Kbase + (long)(kt * 64 + sr1) * 1024 + sc1);
        short8 v0 = *(const short8*)(Vbase + (long)sr0 * 512 + kt * 64 + sc0);
        short8 v1 = *(const short8*)(Vbase + (long)sr1 * 512 + kt * 64 + sc1);
        short8 g0 = *(const short8*)(Gbase + (long)sr0 * 512 + kt * 64 + sc0);
        short8 g1 = *(const short8*)(Gbase + (long)sr1 * 512 + kt * 64 + sc1);
        *(short8*)&Ks[sr0][sc0] = k0;
        *(short8*)&Ks[sr1][sc1] = k1;
        *(short8*)&Vs[sr0][sc0] = v0;
        *(short8*)&Vs[sr1][sc1] = v1;
        *(short8*)&Gs[sr0][sc0] = g0;
        *(short8*)&Gs[sr1][sc1] = g1;
        __syncthreads();

        f32x4 sc[4];
        #pragma unroll
        for (int nk = 0; nk < 4; ++nk) {
            bf16x8 bk0 = *(const bf16x8*)&Ks[nk * 16 + l16][quad * 8];
            bf16x8 bk1 = *(const bf16x8*)&Ks[nk * 16 + l16][32 + quad * 8];
            f32x4 s = (f32x4){0.f, 0.f, 0.f, 0.f};
            s = __builtin_amdgcn_mfma_f32_16x16x32_bf16(aq0, bk0, s, 0, 0, 0);
            s = __builtin_amdgcn_mfma_f32_16x16x32_bf16(aq1, bk1, s, 0, 0, 0);
            sc[nk] = s;
        }
        #pragma unroll
        for (int nk = 0; nk < 4; ++nk)
            #pragma unroll
            for (int r = 0; r < 4; ++r)
                Pbuf[wave][quad * 4 + r][nk * 16 + l16] = (_Float16)__expf(sc[nk][r] * 0.125f);
        f16x8 ep0 = *(const f16x8*)&Pbuf[wave][l16][quad * 8];
        f16x8 ep1 = *(const f16x8*)&Pbuf[wave][l16][32 + quad * 8];
        f16x8 gA = *(const f16x8*)&Gs[wave * 16 + l16][quad * 8];
        f16x8 gB = *(const f16x8*)&Gs[wave * 16 + l16][32 + quad * 8];
        f16x8 gp0 = ep0 * gA;
        f16x8 gp1 = ep1 * gB;
        float part = 0.f;
        #pragma unroll
        for (int j = 0; j < 8; ++j) part += (float)gp0[j] + (float)gp1[j];
        rs += part;
        #pragma unroll
        for (int n4 = 0; n4 < 4; ++n4) {
            f16x8 bv0 = *(const f16x8*)&Vs[n4 * 16 + l16][quad * 8];
            f16x8 bv1 = *(const f16x8*)&Vs[n4 * 16 + l16][32 + quad * 8];
            oacc[n4] = __builtin_amdgcn_mfma_f32_16x16x32_f16(gp0, bv0, oacc[n4], 0, 0, 0);
            oacc[n4] = __builtin_amdgcn_mfma_f32_16x16x32_f16(gp1, bv1, oacc[n4], 0, 0, 0);
        }
    }

    rs += __shfl_xor(rs, 16);
    rs += __shfl_xor(rs, 32);
    float li[4];
    #pragma unroll
    for (int r = 0; r < 4; ++r) li[r] = __shfl(rs, quad * 4 + r);

    #pragma unroll
    for (int n4 = 0; n4 < 4; ++n4)
        #pragma unroll
        for (int r = 0; r < 4; ++r) {
            float o = oacc[n4][r] / li[r];
            O[((long)(b * 512 + qrow + quad * 4 + r)) * 1024 + h * 64 + n4 * 16 + l16] = f2bf(o);
        }
}

// ---------- K4: Wo GEMM, 128x64 tiles, 3-buffer prefetch + XCD swizzle (flat 512-block grid) ----------
#define GOUT_COMP(BC)                                                                  \
    {                                                                                  \
        bf16x8 a_[2], bb_[4];                                                          \
        _Pragma("unroll")                                                              \
        for (int g = 0; g < 2; ++g)                                                    \
            a_[g] = *(const bf16x8*)&As[BC][(mw + g * 16 + l16) * 32 + quad * 8];      \
        _Pragma("unroll")                                                              \
        for (int g = 0; g < 4; ++g)                                                    \
            bb_[g] = *(const bf16x8*)&Bs[BC][(g * 16 + l16) * 32 + quad * 8];          \
        _Pragma("unroll")                                                              \
        for (int mg = 0; mg < 2; ++mg)                                                 \
            _Pragma("unroll")                                                          \
            for (int ng = 0; ng < 4; ++ng)                                             \
                acc[mg][ng] = __builtin_amdgcn_mfma_f32_16x16x32_bf16(a_[mg], bb_[ng], acc[mg][ng], 0, 0, 0); \
    }

#define GOUT_STEP(T, BC, BS)                                                           \
    {                                                                                  \
        asm volatile("s_waitcnt vmcnt(3)" ::: "memory");                               \
        __builtin_amdgcn_s_barrier();                                                  \
        const int k1_ = ((T) + 2) * 32;                                                \
        load_lds16(ga0 + k1_, &As[BS][wb]);                                            \
        load_lds16(ga1 + k1_, &As[BS][2048 + wb]);                                     \
        load_lds16(gb0 + k1_, &Bs[BS][wb]);                                            \
        GOUT_COMP(BC)                                                                  \
    }

__global__ __launch_bounds__(256, 4)
void gemm_out3(const short* __restrict__ Hd, const short* __restrict__ wob,
               const float* __restrict__ bo, float* __restrict__ out) {
    __shared__ __align__(16) short As[3][4096];   // 3 x [128][32]
    __shared__ __align__(16) short Bs[3][2048];   // 3 x [64][32]
    const int tid = threadIdx.x;
    const int wave = tid >> 6, lane = tid & 63, quad = lane >> 4, l16 = lane & 15;
    // 512 blocks = 8 x 64-chunk XCD swizzle; 16 consecutive logical ids share A panel.
    // NOTE: grid MUST be flat 512 x 1 (r3 bug: 2-D grid left blockIdx.y unused -> 97% unwritten).
    const int bid = (blockIdx.x & 7) * 64 + (blockIdx.x >> 3);
    const int m0 = (bid >> 4) * 128, n0 = (bid & 15) * 64;
    const short* Ap = Hd + (long)m0 * 1024;
    const short* Bp = wob + (long)n0 * 1024;

    f32x4 acc[2][4];
    #pragma unroll
    for (int mg = 0; mg < 2; ++mg)
        #pragma unroll
        for (int ng = 0; ng < 4; ++ng) acc[mg][ng] = (f32x4){0.f, 0.f, 0.f, 0.f};

    const int r0 = tid >> 2, kk = (tid & 3) * 8;
    const short* ga0 = Ap + (long)r0 * 1024 + kk;
    const short* ga1 = Ap + (long)(64 + r0) * 1024 + kk;
    const short* gb0 = Bp + (long)r0 * 1024 + kk;
    const int wb = wave * 512;
    const int mw = wave * 32;

    // prologue: stage tiles 0 and 1
    load_lds16(ga0, &As[0][wb]);
    load_lds16(ga1, &As[0][2048 + wb]);
    load_lds16(gb0, &Bs[0][wb]);
    load_lds16(ga0 + 32, &As[1][wb]);
    load_lds16(ga1 + 32, &As[1][2048 + wb]);
    load_lds16(gb0 + 32, &Bs[1][wb]);

    for (int tb = 0; tb < 30; tb += 3) {
        GOUT_STEP(tb,     0, 2)
        GOUT_STEP(tb + 1, 1, 0)
        GOUT_STEP(tb + 2, 2, 1)
    }
    asm volatile("s_waitcnt vmcnt(3)" ::: "memory");
    __builtin_amdgcn_s_barrier();
    GOUT_COMP(0)
    asm volatile("s_waitcnt vmcnt(0)" ::: "memory");
    __builtin_amdgcn_s_barrier();
    GOUT_COMP(1)

    #pragma unroll
    for (int mg = 0; mg < 2; ++mg)
        #pragma unroll
        for (int ng = 0; ng < 4; ++ng)
            #pragma unroll
            for (int r = 0; r < 4; ++r) {
                int row = m0 + mw + mg * 16 + quad * 4 + r;
                int col = n0 + ng * 16 + l16;
                out[(long)row * 1024 + col] = acc[mg][ng][r] + bo[col];
            }
}

// ---------- launch ----------
extern "C" void kernel_launch(void* const* d_in, const int* in_sizes, int n_in,
                              void* d_out, int out_size, void* d_ws, size_t ws_size,
                              hipStream_t stream) {
    const float* queries = (const float*)d_in[0];
    const float* keys    = (const float*)d_in[1];
    const float* values  = (const float*)d_in[2];
    const float* boxes   = (const float*)d_in[3];
    const float* bq = (const float*)d_in[5];
    const float* bk = (const float*)d_in[7];
    const float* bv = (const float*)d_in[9];
    const float* bo = (const float*)d_in[11];
    const float* Wg = (const float*)d_in[12];
    const float* bg = (const float*)d_in[13];

    char* ws = (char*)d_ws;
    short* qbf = (short*)(ws + 0);
    short* kbf = (short*)(ws + 8388608);
    short* vbf = (short*)(ws + 16777216);
    short* wqb = (short*)(ws + 25165824);    // wqb/wkb adjacent (z-stride 1048576 elems)
    short* wkb = (short*)(ws + 27262976);
    short* wvb = (short*)(ws + 29360128);
    short* wob = (short*)(ws + 31457280);
    short* Qh  = (short*)(ws + 33554432);    // Qh/Kh adjacent (z-stride 4194304 elems)
    _Float16* Vt = (_Float16*)(ws + 50331648);  // [b][1024 out][512 tok] f16
    short* Hd  = (short*)(ws + 58720256);    // hidden [4096][1024]
    __half* G  = (__half*)(ws + 67108864);   // g [b][h][512][512] f16, 67 MB
    _Float16* Wgh = (_Float16*)(ws + 33554432);  // overlaps Qh (dead before proj)

    convert_qkv<<<dim3(4096, 3), 256, 0, stream>>>(queries, keys, values, qbf, kbf, vbf);
    convert_w4<<<dim3(1024, 4), 256, 0, stream>>>((const float*)d_in[4], (const float*)d_in[6],
                                                  (const float*)d_in[8], (const float*)d_in[10],
                                                  wqb, wkb, wvb, wob);
    convert_f32_f16<<<4, 256, 0, stream>>>(Wg, Wgh, 1024);

    geom_kernel4<<<dim3(8, 64, 8), 256, 0, stream>>>(boxes, Wgh, bg, G);

    // all projections: 768 blocks, 128x128 tiles, 3-deep prefetch, XCD swizzle
    proj_all5<<<768, 256, 0, stream>>>(qbf, wqb, wvb, vbf, bq, bk, bv, Qh, Vt);

    flash_attn6<<<dim3(8, 16, 8), 256, 0, stream>>>(Qh, Qh + 4194304, Vt, G, Hd);

    // output projection -> f32 + bias, FLAT 512-block grid (matches 1-D swizzle)
    gemm_out3<<<512, 256, 0, stream>>>(Hd, wob, bo, (float*)d_out);
}

// Round 5
// 257.674 us; speedup vs baseline: 1.0698x; 1.0051x over previous
//
#include <hip/hip_runtime.h>
#include <hip/hip_bf16.h>
#include <hip/hip_fp16.h>

// ---------- common types ----------
typedef __attribute__((ext_vector_type(8))) short bf16x8;      // 8 bf16 = 4 VGPR (MFMA A/B frag)
typedef __attribute__((ext_vector_type(8))) _Float16 f16x8;    // 8 f16  = 4 VGPR (MFMA A/B frag)
typedef __attribute__((ext_vector_type(4))) float f32x4;       // MFMA C/D frag
typedef __attribute__((ext_vector_type(8))) short short8;      // 16B chunk

__device__ __forceinline__ short f2bf(float x) {
    unsigned u = __builtin_bit_cast(unsigned, x);
    u += 0x7fffu + ((u >> 16) & 1u);          // RNE
    return (short)(u >> 16);
}

// async global->LDS, 16B per lane. lds dst must be wave-uniform base; HW scatters lane*16.
__device__ __forceinline__ void load_lds16(const void* g, void* l) {
    __builtin_amdgcn_global_load_lds((const __attribute__((address_space(1))) unsigned int*)g,
                                     (__attribute__((address_space(3))) unsigned int*)l, 16, 0, 0);
}

// ---------- K0: fused converts ----------
__global__ void convert_qkv(const float* __restrict__ q, const float* __restrict__ k,
                            const float* __restrict__ v, short* __restrict__ qo,
                            short* __restrict__ ko, short* __restrict__ vo) {
    int i = blockIdx.x * 256 + threadIdx.x;   // 1048576 float4 per tensor, grid (4096,3)
    const float* s = blockIdx.y == 0 ? q : blockIdx.y == 1 ? k : v;
    short* d = blockIdx.y == 0 ? qo : blockIdx.y == 1 ? ko : vo;
    float4 val = reinterpret_cast<const float4*>(s)[i];
    short4 o; o.x = f2bf(val.x); o.y = f2bf(val.y); o.z = f2bf(val.z); o.w = f2bf(val.w);
    reinterpret_cast<short4*>(d)[i] = o;
}

__global__ void convert_w4(const float* __restrict__ w0, const float* __restrict__ w1,
                           const float* __restrict__ w2, const float* __restrict__ w3,
                           short* __restrict__ o0, short* __restrict__ o1,
                           short* __restrict__ o2, short* __restrict__ o3) {
    int i = blockIdx.x * 256 + threadIdx.x;   // 262144 float4 per tensor, grid (1024,4)
    const float* s = blockIdx.y == 0 ? w0 : blockIdx.y == 1 ? w1 : blockIdx.y == 2 ? w2 : w3;
    short* d = blockIdx.y == 0 ? o0 : blockIdx.y == 1 ? o1 : blockIdx.y == 2 ? o2 : o3;
    float4 val = reinterpret_cast<const float4*>(s)[i];
    short4 o; o.x = f2bf(val.x); o.y = f2bf(val.y); o.z = f2bf(val.z); o.w = f2bf(val.w);
    reinterpret_cast<short4*>(d)[i] = o;
}

__global__ void convert_f32_f16(const float* __restrict__ src, _Float16* __restrict__ dst, int n) {
    int i = blockIdx.x * blockDim.x + threadIdx.x;
    if (i < n) dst[i] = (_Float16)src[i];
}

// ---------- K1: geometry bias. 64 m x 8 n per block ----------
__global__ __launch_bounds__(256)
void geom_kernel4(const float* __restrict__ boxes, const _Float16* __restrict__ Wgh,
                  const float* __restrict__ bg, __half* __restrict__ G) {
    const int tid = threadIdx.x;
    const int wave = tid >> 6, lane = tid & 63, quad = lane >> 4, l16 = lane & 15;
    const int m0 = blockIdx.x * 64;
    const int n0 = blockIdx.y * 8;
    const int b = blockIdx.z;

    __shared__ __align__(16) _Float16 feat[4][16][72];
    __shared__ __align__(16) _Float16 gbuf[16][68];

    const int p = lane >> 2, c = lane & 3;
    const int m = m0 + wave * 16 + p;

    // m-side (per-thread, hoisted)
    float4 bm = reinterpret_cast<const float4*>(boxes)[b * 512 + m];
    float cxm = (bm.x + bm.z) * 0.5f, cym = (bm.y + bm.w) * 0.5f;
    float wm = bm.z - bm.x + 1.0f, hm = bm.w - bm.y + 1.0f;
    float lwm = __logf(wm), lhm = __logf(hm);

    // Wg fragments (constant across n) + bias
    f16x8 wb0 = *(const f16x8*)(Wgh + l16 * 64 + quad * 8);
    f16x8 wb1 = *(const f16x8*)(Wgh + l16 * 64 + 32 + quad * 8);
    float bgv = bg[l16];

    const float dm[8] = {1.0f, 0.42169651f, 0.17782794f, 0.07498942f,
                         0.03162278f, 0.01333521f, 0.00562341f, 0.00237137f};
    const int h = tid >> 4, seg = tid & 15;

    for (int ni = 0; ni < 8; ++ni) {
        const int n = n0 + ni;
        float4 bn = reinterpret_cast<const float4*>(boxes)[b * 512 + n];   // uniform
        float cxn = (bn.x + bn.z) * 0.5f, cyn = (bn.y + bn.w) * 0.5f;
        float wn = bn.z - bn.x + 1.0f, hn = bn.w - bn.y + 1.0f;
        float lwn = __logf(wn), lhn = __logf(hn);

        // channel c: 0:|cxn-cxm|/wn  1:|cyn-cym|/hn  2:wn/wm  3:hn/hm
        float numa = (c == 1) ? fabsf(cyn - cym) : fabsf(cxn - cxm);
        float pl = fmaxf(__logf(numa) - ((c == 1) ? lhn : lwn), -6.9077552790f);  // log(1e-3)
        float sl = (c == 3) ? (lhn - lhm) : (lwn - lwm);
        float pos = ((c < 2) ? pl : sl) * 100.0f;

        f16x8 sv8, cv8;
        #pragma unroll
        for (int f = 0; f < 8; ++f) {
            float th = pos * dm[f];
            sv8[f] = (_Float16)__sinf(th);
            cv8[f] = (_Float16)__cosf(th);
        }
        *(f16x8*)&feat[wave][p][c * 8]      = sv8;
        *(f16x8*)&feat[wave][p][32 + c * 8] = cv8;

        __syncthreads();

        f16x8 a0 = *(const f16x8*)&feat[wave][l16][quad * 8];
        f16x8 a1 = *(const f16x8*)&feat[wave][l16][32 + quad * 8];
        f32x4 acc = (f32x4){0.f, 0.f, 0.f, 0.f};
        acc = __builtin_amdgcn_mfma_f32_16x16x32_f16(a0, wb0, acc, 0, 0, 0);
        acc = __builtin_amdgcn_mfma_f32_16x16x32_f16(a1, wb1, acc, 0, 0, 0);

        #pragma unroll
        for (int rr = 0; rr < 4; ++rr) {
            float g = fmaxf(acc[rr] + bgv, 1e-6f);        // relu + clip; store g itself
            gbuf[l16][wave * 16 + quad * 4 + rr] = (_Float16)g;
        }
        __syncthreads();

        ushort4 v = *(const ushort4*)&gbuf[h][seg * 4];
        *(ushort4*)&G[((long)((b * 16 + h) * 512 + n)) * 512 + m0 + seg * 4] = v;
    }
}

// ---------- K2: projections, 128x128 tiles, 3-buffer prefetch + XCD swizzle + T2 LDS swizzle ----------
// LDS layout: [128][32] bf16 = 512 granules of 16B; logical granule gl = row*4 + quad.
// Physical slot gp = gl ^ ((gl>>3)&7)  — involution (XOR value from untouched high bits).
// global_load_lds writes linearly, so the GLOBAL per-lane source is permuted with the same
// involution (j = lane ^ ((lane>>3)&7)); ds_read applies the XOR on its address.
// Result: each 8-lane phase of a ds_read_b128 covers all 32 banks (was 8-way conflicted).
#define PROJ_COMP(BC)                                                                  \
    {                                                                                  \
        bf16x8 a_[4], bb_[4];                                                          \
        _Pragma("unroll")                                                              \
        for (int g = 0; g < 4; ++g) {                                                  \
            int gl = (wr * 64 + g * 16 + l16) * 4 + quad;                              \
            gl ^= (gl >> 3) & 7;                                                       \
            a_[g] = *(const bf16x8*)&As[BC][gl * 8];                                   \
        }                                                                              \
        _Pragma("unroll")                                                              \
        for (int g = 0; g < 4; ++g) {                                                  \
            int gl = (wc * 64 + g * 16 + l16) * 4 + quad;                              \
            gl ^= (gl >> 3) & 7;                                                       \
            bb_[g] = *(const bf16x8*)&Bs[BC][gl * 8];                                  \
        }                                                                              \
        _Pragma("unroll")                                                              \
        for (int mg = 0; mg < 4; ++mg)                                                 \
            _Pragma("unroll")                                                          \
            for (int ng = 0; ng < 4; ++ng)                                             \
                acc[mg][ng] = __builtin_amdgcn_mfma_f32_16x16x32_bf16(a_[mg], bb_[ng], acc[mg][ng], 0, 0, 0); \
    }

#define PROJ_STEP(T, BC, BS)                                                           \
    {                                                                                  \
        asm volatile("s_waitcnt vmcnt(4)" ::: "memory");                               \
        __builtin_amdgcn_s_barrier();                                                  \
        const int k1_ = ((T) + 2) * 32;                                                \
        load_lds16(ga0 + k1_, &As[BS][wb]);                                            \
        load_lds16(ga1 + k1_, &As[BS][2048 + wb]);                                     \
        load_lds16(gb0 + k1_, &Bs[BS][wb]);                                            \
        load_lds16(gb1 + k1_, &Bs[BS][2048 + wb]);                                     \
        PROJ_COMP(BC)                                                                  \
    }

__global__ __launch_bounds__(256, 3)
void proj_all6(const short* __restrict__ qkbf, const short* __restrict__ wqkb,
               const short* __restrict__ wvb, const short* __restrict__ vbf,
               const float* __restrict__ bq, const float* __restrict__ bk,
               const float* __restrict__ bv,
               short* __restrict__ QKh, _Float16* __restrict__ Vt) {
    __shared__ __align__(16) short As[3][4096];   // 3 x [128][32] (swizzled granules)
    __shared__ __align__(16) short Bs[3][4096];
    const int tid = threadIdx.x;
    const int wave = tid >> 6, lane = tid & 63, quad = lane >> 4, l16 = lane & 15;
    // T1 XCD swizzle: 768 blocks = 8 XCDs x 96-chunk (bijective).
    const int bid = (blockIdx.x & 7) * 96 + (blockIdx.x >> 3);

    const short *Ap, *Bp;
    int m0, n0, z = 0;
    bool isV = bid >= 512;
    if (!isV) {
        z = bid >> 8;
        int t = bid & 255;
        n0 = (t & 7) * 128; m0 = (t >> 3) * 128;      // 8 consecutive share token panel
        Ap = qkbf + (long)z * 4194304 + (long)m0 * 1024;
        Bp = wqkb + (long)z * 1048576 + (long)n0 * 1024;
    } else {
        int t = bid - 512;
        m0 = (t & 7) * 128; n0 = (t >> 3) * 128;      // 8 consecutive share token panel (vbf)
        Ap = wvb + (long)m0 * 1024;
        Bp = vbf + (long)n0 * 1024;
    }

    f32x4 acc[4][4];
    #pragma unroll
    for (int mg = 0; mg < 4; ++mg)
        #pragma unroll
        for (int ng = 0; ng < 4; ++ng) acc[mg][ng] = (f32x4){0.f, 0.f, 0.f, 0.f};

    // stage source permuted by the involution; same cache-line set per 8-lane group.
    const int lj = lane ^ ((lane >> 3) & 7);
    const int r0 = wave * 16 + (lj >> 2), kk = (lj & 3) * 8;
    const short* ga0 = Ap + (long)r0 * 1024 + kk;
    const short* ga1 = Ap + (long)(64 + r0) * 1024 + kk;
    const short* gb0 = Bp + (long)r0 * 1024 + kk;
    const short* gb1 = Bp + (long)(64 + r0) * 1024 + kk;
    const int wb = wave * 512;
    const int wr = wave >> 1, wc = wave & 1;   // 2x2 wave grid, 64x64 per wave

    // prologue: stage tiles 0 and 1 (tile-0 loads issued first => oldest for vmcnt)
    load_lds16(ga0, &As[0][wb]);
    load_lds16(ga1, &As[0][2048 + wb]);
    load_lds16(gb0, &Bs[0][wb]);
    load_lds16(gb1, &Bs[0][2048 + wb]);
    load_lds16(ga0 + 32, &As[1][wb]);
    load_lds16(ga1 + 32, &As[1][2048 + wb]);
    load_lds16(gb0 + 32, &Bs[1][wb]);
    load_lds16(gb1 + 32, &Bs[1][2048 + wb]);

    for (int tb = 0; tb < 30; tb += 3) {   // steps 0..29, staging tiles 2..31
        PROJ_STEP(tb,     0, 2)
        PROJ_STEP(tb + 1, 1, 0)
        PROJ_STEP(tb + 2, 2, 1)
    }
    // tail: t=30 (buf 0), t=31 (buf 1), no staging
    asm volatile("s_waitcnt vmcnt(4)" ::: "memory");
    __builtin_amdgcn_s_barrier();
    PROJ_COMP(0)
    asm volatile("s_waitcnt vmcnt(0)" ::: "memory");
    __builtin_amdgcn_s_barrier();
    PROJ_COMP(1)

    #pragma unroll
    for (int mg = 0; mg < 4; ++mg)
        #pragma unroll
        for (int ng = 0; ng < 4; ++ng)
            #pragma unroll
            for (int r = 0; r < 4; ++r) {
                int row = m0 + wr * 64 + mg * 16 + quad * 4 + r;
                int col = n0 + wc * 64 + ng * 16 + l16;
                if (!isV) {
                    float v = acc[mg][ng][r] + (z ? bk[col] : bq[col]);
                    QKh[(long)z * 4194304 + (long)row * 1024 + col] = f2bf(v);
                } else {
                    float v = acc[mg][ng][r] + bv[row];
                    int bcol = col >> 9, lc = col & 511;    // token -> (batch, local)
                    Vt[(long)bcol * 524288 + (long)row * 512 + lc] = (_Float16)v;
                }
            }
}

// ---------- K3: flash attention, m97-style cooperative LDS staging ----------
__global__ __launch_bounds__(256, 4)
void flash_attn6(const short* __restrict__ Q, const short* __restrict__ Kh,
                 const _Float16* __restrict__ Vt, const __half* __restrict__ G,
                 short* __restrict__ O) {
    const int tid = threadIdx.x;
    const int wave = tid >> 6, lane = tid & 63, quad = lane >> 4, l16 = lane & 15;
    const int qt = blockIdx.x, h = blockIdx.y, b = blockIdx.z;

    __shared__ __align__(16) short    Ks[64][72];        // [kv][d]
    __shared__ __align__(16) _Float16 Vs[64][72];        // [d][kv]
    __shared__ __align__(16) _Float16 Gs[64][72];        // [q][kv]
    __shared__ __align__(16) _Float16 Pbuf[4][16][72];   // per-wave private

    const int qrow = qt * 64 + wave * 16;
    const long qoff = ((long)(b * 512 + qrow + l16)) * 1024 + h * 64 + quad * 8;
    bf16x8 aq0 = *(const bf16x8*)(Q + qoff);
    bf16x8 aq1 = *(const bf16x8*)(Q + qoff + 32);

    const int sr0 = tid >> 3,         sc0 = (tid & 7) * 8;
    const int sr1 = (tid + 256) >> 3, sc1 = ((tid + 256) & 7) * 8;
    const short* Kbase = Kh + (long)(b * 512) * 1024 + h * 64;
    const _Float16* Vbase = Vt + (long)b * 524288 + (long)(h * 64) * 512;
    const _Float16* Gbase = (const _Float16*)G + ((long)((b * 16 + h) * 512 + qt * 64)) * 512;

    f32x4 oacc[4];
    #pragma unroll
    for (int r = 0; r < 4; ++r) oacc[r] = (f32x4){0.f, 0.f, 0.f, 0.f};
    float rs = 0.f;

    for (int kt = 0; kt < 8; ++kt) {
        __syncthreads();
        short8 k0 = *(const short8*)(Kbase + (long)(kt * 64 + sr0) * 1024 + sc0);
        short8 k1 = *(const short8*)(Kbase + (long)(kt * 64 + sr1) * 1024 + sc1);
        short8 v0 = *(const short8*)(Vbase + (long)sr0 * 512 + kt * 64 + sc0);
        short8 v1 = *(const short8*)(Vbase + (long)sr1 * 512 + kt * 64 + sc1);
        short8 g0 = *(const short8*)(Gbase + (long)sr0 * 512 + kt * 64 + sc0);
        short8 g1 = *(const short8*)(Gbase + (long)sr1 * 512 + kt * 64 + sc1);
        *(short8*)&Ks[sr0][sc0] = k0;
        *(short8*)&Ks[sr1][sc1] = k1;
        *(short8*)&Vs[sr0][sc0] = v0;
        *(short8*)&Vs[sr1][sc1] = v1;
        *(short8*)&Gs[sr0][sc0] = g0;
        *(short8*)&Gs[sr1][sc1] = g1;
        __syncthreads();

        f32x4 sc[4];
        #pragma unroll
        for (int nk = 0; nk < 4; ++nk) {
            bf16x8 bk0 = *(const bf16x8*)&Ks[nk * 16 + l16][quad * 8];
            bf16x8 bk1 = *(const bf16x8*)&Ks[nk * 16 + l16][32 + quad * 8];
            f32x4 s = (f32x4){0.f, 0.f, 0.f, 0.f};
            s = __builtin_amdgcn_mfma_f32_16x16x32_bf16(aq0, bk0, s, 0, 0, 0);
            s = __builtin_amdgcn_mfma_f32_16x16x32_bf16(aq1, bk1, s, 0, 0, 0);
            sc[nk] = s;
        }
        #pragma unroll
        for (int nk = 0; nk < 4; ++nk)
            #pragma unroll
            for (int r = 0; r < 4; ++r)
                Pbuf[wave][quad * 4 + r][nk * 16 + l16] = (_Float16)__expf(sc[nk][r] * 0.125f);
        f16x8 ep0 = *(const f16x8*)&Pbuf[wave][l16][quad * 8];
        f16x8 ep1 = *(const f16x8*)&Pbuf[wave][l16][32 + quad * 8];
        f16x8 gA = *(const f16x8*)&Gs[wave * 16 + l16][quad * 8];
        f16x8 gB = *(const f16x8*)&Gs[wave * 16 + l16][32 + quad * 8];
        f16x8 gp0 = ep0 * gA;
        f16x8 gp1 = ep1 * gB;
        float part = 0.f;
        #pragma unroll
        for (int j = 0; j < 8; ++j) part += (float)gp0[j] + (float)gp1[j];
        rs += part;
        #pragma unroll
        for (int n4 = 0; n4 < 4; ++n4) {
            f16x8 bv0 = *(const f16x8*)&Vs[n4 * 16 + l16][quad * 8];
            f16x8 bv1 = *(const f16x8*)&Vs[n4 * 16 + l16][32 + quad * 8];
            oacc[n4] = __builtin_amdgcn_mfma_f32_16x16x32_f16(gp0, bv0, oacc[n4], 0, 0, 0);
            oacc[n4] = __builtin_amdgcn_mfma_f32_16x16x32_f16(gp1, bv1, oacc[n4], 0, 0, 0);
        }
    }

    rs += __shfl_xor(rs, 16);
    rs += __shfl_xor(rs, 32);
    float li[4];
    #pragma unroll
    for (int r = 0; r < 4; ++r) li[r] = __shfl(rs, quad * 4 + r);

    #pragma unroll
    for (int n4 = 0; n4 < 4; ++n4)
        #pragma unroll
        for (int r = 0; r < 4; ++r) {
            float o = oacc[n4][r] / li[r];
            O[((long)(b * 512 + qrow + quad * 4 + r)) * 1024 + h * 64 + n4 * 16 + l16] = f2bf(o);
        }
}

// ---------- K4: Wo GEMM, 128x64 tiles, 3-buffer prefetch + XCD swizzle + T2 LDS swizzle ----------
#define GOUT_COMP(BC)                                                                  \
    {                                                                                  \
        bf16x8 a_[2], bb_[4];                                                          \
        _Pragma("unroll")                                                              \
        for (int g = 0; g < 2; ++g) {                                                  \
            int gl = (mw + g * 16 + l16) * 4 + quad;                                   \
            gl ^= (gl >> 3) & 7;                                                       \
            a_[g] = *(const bf16x8*)&As[BC][gl * 8];                                   \
        }                                                                              \
        _Pragma("unroll")                                                              \
        for (int g = 0; g < 4; ++g) {                                                  \
            int gl = (g * 16 + l16) * 4 + quad;                                        \
            gl ^= (gl >> 3) & 7;                                                       \
            bb_[g] = *(const bf16x8*)&Bs[BC][gl * 8];                                  \
        }                                                                              \
        _Pragma("unroll")                                                              \
        for (int mg = 0; mg < 2; ++mg)                                                 \
            _Pragma("unroll")                                                          \
            for (int ng = 0; ng < 4; ++ng)                                             \
                acc[mg][ng] = __builtin_amdgcn_mfma_f32_16x16x32_bf16(a_[mg], bb_[ng], acc[mg][ng], 0, 0, 0); \
    }

#define GOUT_STEP(T, BC, BS)                                                           \
    {                                                                                  \
        asm volatile("s_waitcnt vmcnt(3)" ::: "memory");                               \
        __builtin_amdgcn_s_barrier();                                                  \
        const int k1_ = ((T) + 2) * 32;                                                \
        load_lds16(ga0 + k1_, &As[BS][wb]);                                            \
        load_lds16(ga1 + k1_, &As[BS][2048 + wb]);                                     \
        load_lds16(gb0 + k1_, &Bs[BS][wb]);                                            \
        GOUT_COMP(BC)                                                                  \
    }

__global__ __launch_bounds__(256, 4)
void gemm_out4(const short* __restrict__ Hd, const short* __restrict__ wob,
               const float* __restrict__ bo, float* __restrict__ out) {
    __shared__ __align__(16) short As[3][4096];   // 3 x [128][32] (swizzled granules)
    __shared__ __align__(16) short Bs[3][2048];   // 3 x [64][32]
    const int tid = threadIdx.x;
    const int wave = tid >> 6, lane = tid & 63, quad = lane >> 4, l16 = lane & 15;
    // 512 blocks = 8 x 64-chunk XCD swizzle; FLAT 512-block grid required.
    const int bid = (blockIdx.x & 7) * 64 + (blockIdx.x >> 3);
    const int m0 = (bid >> 4) * 128, n0 = (bid & 15) * 64;
    const short* Ap = Hd + (long)m0 * 1024;
    const short* Bp = wob + (long)n0 * 1024;

    f32x4 acc[2][4];
    #pragma unroll
    for (int mg = 0; mg < 2; ++mg)
        #pragma unroll
        for (int ng = 0; ng < 4; ++ng) acc[mg][ng] = (f32x4){0.f, 0.f, 0.f, 0.f};

    const int lane6 = tid & 63;
    const int lj = lane6 ^ ((lane6 >> 3) & 7);
    const int r0 = wave * 16 + (lj >> 2), kk = (lj & 3) * 8;
    const short* ga0 = Ap + (long)r0 * 1024 + kk;
    const short* ga1 = Ap + (long)(64 + r0) * 1024 + kk;
    const short* gb0 = Bp + (long)r0 * 1024 + kk;
    const int wb = wave * 512;
    const int mw = wave * 32;

    // prologue: stage tiles 0 and 1
    load_lds16(ga0, &As[0][wb]);
    load_lds16(ga1, &As[0][2048 + wb]);
    load_lds16(gb0, &Bs[0][wb]);
    load_lds16(ga0 + 32, &As[1][wb]);
    load_lds16(ga1 + 32, &As[1][2048 + wb]);
    load_lds16(gb0 + 32, &Bs[1][wb]);

    for (int tb = 0; tb < 30; tb += 3) {
        GOUT_STEP(tb,     0, 2)
        GOUT_STEP(tb + 1, 1, 0)
        GOUT_STEP(tb + 2, 2, 1)
    }
    asm volatile("s_waitcnt vmcnt(3)" ::: "memory");
    __builtin_amdgcn_s_barrier();
    GOUT_COMP(0)
    asm volatile("s_waitcnt vmcnt(0)" ::: "memory");
    __builtin_amdgcn_s_barrier();
    GOUT_COMP(1)

    #pragma unroll
    for (int mg = 0; mg < 2; ++mg)
        #pragma unroll
        for (int ng = 0; ng < 4; ++ng)
            #pragma unroll
            for (int r = 0; r < 4; ++r) {
                int row = m0 + mw + mg * 16 + quad * 4 + r;
                int col = n0 + ng * 16 + l16;
                out[(long)row * 1024 + col] = acc[mg][ng][r] + bo[col];
            }
}

// ---------- launch ----------
extern "C" void kernel_launch(void* const* d_in, const int* in_sizes, int n_in,
                              void* d_out, int out_size, void* d_ws, size_t ws_size,
                              hipStream_t stream) {
    const float* queries = (const float*)d_in[0];
    const float* keys    = (const float*)d_in[1];
    const float* values  = (const float*)d_in[2];
    const float* boxes   = (const float*)d_in[3];
    const float* bq = (const float*)d_in[5];
    const float* bk = (const float*)d_in[7];
    const float* bv = (const float*)d_in[9];
    const float* bo = (const float*)d_in[11];
    const float* Wg = (const float*)d_in[12];
    const float* bg = (const float*)d_in[13];

    char* ws = (char*)d_ws;
    short* qbf = (short*)(ws + 0);
    short* kbf = (short*)(ws + 8388608);
    short* vbf = (short*)(ws + 16777216);
    short* wqb = (short*)(ws + 25165824);    // wqb/wkb adjacent (z-stride 1048576 elems)
    short* wkb = (short*)(ws + 27262976);
    short* wvb = (short*)(ws + 29360128);
    short* wob = (short*)(ws + 31457280);
    short* Qh  = (short*)(ws + 33554432);    // Qh/Kh adjacent (z-stride 4194304 elems)
    _Float16* Vt = (_Float16*)(ws + 50331648);  // [b][1024 out][512 tok] f16
    short* Hd  = (short*)(ws + 58720256);    // hidden [4096][1024]
    __half* G  = (__half*)(ws + 67108864);   // g [b][h][512][512] f16, 67 MB
    _Float16* Wgh = (_Float16*)(ws + 33554432);  // overlaps Qh (dead before proj)

    convert_qkv<<<dim3(4096, 3), 256, 0, stream>>>(queries, keys, values, qbf, kbf, vbf);
    convert_w4<<<dim3(1024, 4), 256, 0, stream>>>((const float*)d_in[4], (const float*)d_in[6],
                                                  (const float*)d_in[8], (const float*)d_in[10],
                                                  wqb, wkb, wvb, wob);
    convert_f32_f16<<<4, 256, 0, stream>>>(Wg, Wgh, 1024);

    geom_kernel4<<<dim3(8, 64, 8), 256, 0, stream>>>(boxes, Wgh, bg, G);

    // all projections: 768 blocks, 128x128 tiles, 3-deep prefetch, XCD+LDS swizzle
    proj_all6<<<768, 256, 0, stream>>>(qbf, wqb, wvb, vbf, bq, bk, bv, Qh, Vt);

    flash_attn6<<<dim3(8, 16, 8), 256, 0, stream>>>(Qh, Qh + 4194304, Vt, G, Hd);

    // output projection -> f32 + bias, FLAT 512-block grid
    gemm_out4<<<512, 256, 0, stream>>>(Hd, wob, bo, (float*)d_out);
}

// Round 9
// 256.816 us; speedup vs baseline: 1.0733x; 1.0033x over previous
//
#include <hip/hip_runtime.h>
#include <hip/hip_bf16.h>
#include <hip/hip_fp16.h>

// ---------- common types ----------
typedef __attribute__((ext_vector_type(8))) short bf16x8;      // 8 bf16 = 4 VGPR (MFMA A/B frag)
typedef __attribute__((ext_vector_type(8))) _Float16 f16x8;    // 8 f16  = 4 VGPR (MFMA A/B frag)
typedef __attribute__((ext_vector_type(4))) float f32x4;       // MFMA C/D frag
typedef __attribute__((ext_vector_type(8))) short short8;      // 16B chunk

__device__ __forceinline__ short f2bf(float x) {
    unsigned u = __builtin_bit_cast(unsigned, x);
    u += 0x7fffu + ((u >> 16) & 1u);          // RNE
    return (short)(u >> 16);
}

// async global->LDS, 16B per lane. lds dst must be wave-uniform base; HW scatters lane*16.
__device__ __forceinline__ void load_lds16(const void* g, void* l) {
    __builtin_amdgcn_global_load_lds((const __attribute__((address_space(1))) unsigned int*)g,
                                     (__attribute__((address_space(3))) unsigned int*)l, 16, 0, 0);
}

// ---------- K0: fused converts ----------
__global__ void convert_qkv(const float* __restrict__ q, const float* __restrict__ k,
                            const float* __restrict__ v, short* __restrict__ qo,
                            short* __restrict__ ko, short* __restrict__ vo) {
    int i = blockIdx.x * 256 + threadIdx.x;   // 1048576 float4 per tensor, grid (4096,3)
    const float* s = blockIdx.y == 0 ? q : blockIdx.y == 1 ? k : v;
    short* d = blockIdx.y == 0 ? qo : blockIdx.y == 1 ? ko : vo;
    float4 val = reinterpret_cast<const float4*>(s)[i];
    short4 o; o.x = f2bf(val.x); o.y = f2bf(val.y); o.z = f2bf(val.z); o.w = f2bf(val.w);
    reinterpret_cast<short4*>(d)[i] = o;
}

__global__ void convert_w4(const float* __restrict__ w0, const float* __restrict__ w1,
                           const float* __restrict__ w2, const float* __restrict__ w3,
                           short* __restrict__ o0, short* __restrict__ o1,
                           short* __restrict__ o2, short* __restrict__ o3) {
    int i = blockIdx.x * 256 + threadIdx.x;   // 262144 float4 per tensor, grid (1024,4)
    const float* s = blockIdx.y == 0 ? w0 : blockIdx.y == 1 ? w1 : blockIdx.y == 2 ? w2 : w3;
    short* d = blockIdx.y == 0 ? o0 : blockIdx.y == 1 ? o1 : blockIdx.y == 2 ? o2 : o3;
    float4 val = reinterpret_cast<const float4*>(s)[i];
    short4 o; o.x = f2bf(val.x); o.y = f2bf(val.y); o.z = f2bf(val.z); o.w = f2bf(val.w);
    reinterpret_cast<short4*>(d)[i] = o;
}

__global__ void convert_f32_f16(const float* __restrict__ src, _Float16* __restrict__ dst, int n) {
    int i = blockIdx.x * blockDim.x + threadIdx.x;
    if (i < n) dst[i] = (_Float16)src[i];
}

// ---------- K1: geometry bias. 64 m x 8 n per block (PROVEN r4/r5 version) ----------
// NOTE (r7/r8 lesson): the single-barrier variant (geom_kernel5) raced — cross-LANE
// communication through LDS without a barrier is a data race in the compiler's
// per-thread model (it may hoist feat reads across the unrolled iterations), even
// though same-wave DS ops are in-order at the HW. The __syncthreads here provide
// the required COMPILER ordering, not just cross-wave sync. Do not remove.
__global__ __launch_bounds__(256)
void geom_kernel4(const float* __restrict__ boxes, const _Float16* __restrict__ Wgh,
                  const float* __restrict__ bg, __half* __restrict__ G) {
    const int tid = threadIdx.x;
    const int wave = tid >> 6, lane = tid & 63, quad = lane >> 4, l16 = lane & 15;
    const int m0 = blockIdx.x * 64;
    const int n0 = blockIdx.y * 8;
    const int b = blockIdx.z;

    __shared__ __align__(16) _Float16 feat[4][16][72];
    __shared__ __align__(16) _Float16 gbuf[16][68];

    const int p = lane >> 2, c = lane & 3;
    const int m = m0 + wave * 16 + p;

    // m-side (per-thread, hoisted)
    float4 bm = reinterpret_cast<const float4*>(boxes)[b * 512 + m];
    float cxm = (bm.x + bm.z) * 0.5f, cym = (bm.y + bm.w) * 0.5f;
    float wm = bm.z - bm.x + 1.0f, hm = bm.w - bm.y + 1.0f;
    float lwm = __logf(wm), lhm = __logf(hm);

    // Wg fragments (constant across n) + bias
    f16x8 wb0 = *(const f16x8*)(Wgh + l16 * 64 + quad * 8);
    f16x8 wb1 = *(const f16x8*)(Wgh + l16 * 64 + 32 + quad * 8);
    float bgv = bg[l16];

    const float dm[8] = {1.0f, 0.42169651f, 0.17782794f, 0.07498942f,
                         0.03162278f, 0.01333521f, 0.00562341f, 0.00237137f};
    const int h = tid >> 4, seg = tid & 15;

    for (int ni = 0; ni < 8; ++ni) {
        const int n = n0 + ni;
        float4 bn = reinterpret_cast<const float4*>(boxes)[b * 512 + n];   // uniform
        float cxn = (bn.x + bn.z) * 0.5f, cyn = (bn.y + bn.w) * 0.5f;
        float wn = bn.z - bn.x + 1.0f, hn = bn.w - bn.y + 1.0f;
        float lwn = __logf(wn), lhn = __logf(hn);

        // channel c: 0:|cxn-cxm|/wn  1:|cyn-cym|/hn  2:wn/wm  3:hn/hm
        float numa = (c == 1) ? fabsf(cyn - cym) : fabsf(cxn - cxm);
        float pl = fmaxf(__logf(numa) - ((c == 1) ? lhn : lwn), -6.9077552790f);  // log(1e-3)
        float sl = (c == 3) ? (lhn - lhm) : (lwn - lwm);
        float pos = ((c < 2) ? pl : sl) * 100.0f;

        f16x8 sv8, cv8;
        #pragma unroll
        for (int f = 0; f < 8; ++f) {
            float th = pos * dm[f];
            sv8[f] = (_Float16)__sinf(th);
            cv8[f] = (_Float16)__cosf(th);
        }
        *(f16x8*)&feat[wave][p][c * 8]      = sv8;
        *(f16x8*)&feat[wave][p][32 + c * 8] = cv8;

        __syncthreads();

        f16x8 a0 = *(const f16x8*)&feat[wave][l16][quad * 8];
        f16x8 a1 = *(const f16x8*)&feat[wave][l16][32 + quad * 8];
        f32x4 acc = (f32x4){0.f, 0.f, 0.f, 0.f};
        acc = __builtin_amdgcn_mfma_f32_16x16x32_f16(a0, wb0, acc, 0, 0, 0);
        acc = __builtin_amdgcn_mfma_f32_16x16x32_f16(a1, wb1, acc, 0, 0, 0);

        #pragma unroll
        for (int rr = 0; rr < 4; ++rr) {
            float g = fmaxf(acc[rr] + bgv, 1e-6f);        // relu + clip; store g itself
            gbuf[l16][wave * 16 + quad * 4 + rr] = (_Float16)g;
        }
        __syncthreads();

        ushort4 v = *(const ushort4*)&gbuf[h][seg * 4];
        *(ushort4*)&G[((long)((b * 16 + h) * 512 + n)) * 512 + m0 + seg * 4] = v;
    }
}

// ---------- K2: projections, 128x128 tiles, 3-buffer 2-ahead prefetch + XCD swizzle ----------
// CFENCE after each raw s_barrier: __builtin_amdgcn_s_barrier() is IntrNoMem — not a
// compiler memory fence. The fence pins staging/ds_reads on the correct side of the
// barrier; zero instructions emitted.
#define CFENCE asm volatile("" ::: "memory")

#define PROJ_COMP(BC)                                                                  \
    {                                                                                  \
        bf16x8 a_[4], bb_[4];                                                          \
        _Pragma("unroll")                                                              \
        for (int g = 0; g < 4; ++g)                                                    \
            a_[g] = *(const bf16x8*)&As[BC][(wr * 64 + g * 16 + l16) * 32 + quad * 8]; \
        _Pragma("unroll")                                                              \
        for (int g = 0; g < 4; ++g)                                                    \
            bb_[g] = *(const bf16x8*)&Bs[BC][(wc * 64 + g * 16 + l16) * 32 + quad * 8];\
        _Pragma("unroll")                                                              \
        for (int mg = 0; mg < 4; ++mg)                                                 \
            _Pragma("unroll")                                                          \
            for (int ng = 0; ng < 4; ++ng)                                             \
                acc[mg][ng] = __builtin_amdgcn_mfma_f32_16x16x32_bf16(a_[mg], bb_[ng], acc[mg][ng], 0, 0, 0); \
    }

#define PROJ_STEP(T, BC, BS)                                                           \
    {                                                                                  \
        asm volatile("s_waitcnt vmcnt(4)" ::: "memory");                               \
        __builtin_amdgcn_s_barrier();                                                  \
        CFENCE;                                                                        \
        const int k1_ = ((T) + 2) * 32;                                                \
        load_lds16(ga0 + k1_, &As[BS][wb]);                                            \
        load_lds16(ga1 + k1_, &As[BS][2048 + wb]);                                     \
        load_lds16(gb0 + k1_, &Bs[BS][wb]);                                            \
        load_lds16(gb1 + k1_, &Bs[BS][2048 + wb]);                                     \
        PROJ_COMP(BC)                                                                  \
    }

__global__ __launch_bounds__(256, 3)
void proj_all7(const short* __restrict__ qkbf, const short* __restrict__ wqkb,
               const short* __restrict__ wvb, const short* __restrict__ vbf,
               const float* __restrict__ bq, const float* __restrict__ bk,
               const float* __restrict__ bv,
               short* __restrict__ QKh, _Float16* __restrict__ Vt) {
    __shared__ __align__(16) short As[3][4096];   // 3 x [128][32]
    __shared__ __align__(16) short Bs[3][4096];
    const int tid = threadIdx.x;
    const int wave = tid >> 6, lane = tid & 63, quad = lane >> 4, l16 = lane & 15;
    // T1 XCD swizzle: 768 blocks = 8 XCDs x 96-chunk (bijective).
    const int bid = (blockIdx.x & 7) * 96 + (blockIdx.x >> 3);

    const short *Ap, *Bp;
    int m0, n0, z = 0;
    bool isV = bid >= 512;
    if (!isV) {
        z = bid >> 8;
        int t = bid & 255;
        n0 = (t & 7) * 128; m0 = (t >> 3) * 128;      // 8 consecutive share token panel
        Ap = qkbf + (long)z * 4194304 + (long)m0 * 1024;
        Bp = wqkb + (long)z * 1048576 + (long)n0 * 1024;
    } else {
        int t = bid - 512;
        m0 = (t & 7) * 128; n0 = (t >> 3) * 128;      // 8 consecutive share token panel (vbf)
        Ap = wvb + (long)m0 * 1024;
        Bp = vbf + (long)n0 * 1024;
    }

    f32x4 acc[4][4];
    #pragma unroll
    for (int mg = 0; mg < 4; ++mg)
        #pragma unroll
        for (int ng = 0; ng < 4; ++ng) acc[mg][ng] = (f32x4){0.f, 0.f, 0.f, 0.f};

    const int r0 = tid >> 2, kk = (tid & 3) * 8;
    const short* ga0 = Ap + (long)r0 * 1024 + kk;
    const short* ga1 = Ap + (long)(64 + r0) * 1024 + kk;
    const short* gb0 = Bp + (long)r0 * 1024 + kk;
    const short* gb1 = Bp + (long)(64 + r0) * 1024 + kk;
    const int wb = wave * 512;
    const int wr = wave >> 1, wc = wave & 1;   // 2x2 wave grid, 64x64 per wave

    // prologue: stage tiles 0 and 1 (tile-0 loads issued first => oldest for vmcnt)
    load_lds16(ga0, &As[0][wb]);
    load_lds16(ga1, &As[0][2048 + wb]);
    load_lds16(gb0, &Bs[0][wb]);
    load_lds16(gb1, &Bs[0][2048 + wb]);
    load_lds16(ga0 + 32, &As[1][wb]);
    load_lds16(ga1 + 32, &As[1][2048 + wb]);
    load_lds16(gb0 + 32, &Bs[1][wb]);
    load_lds16(gb1 + 32, &Bs[1][2048 + wb]);

    for (int tb = 0; tb < 30; tb += 3) {   // steps 0..29, staging tiles 2..31
        PROJ_STEP(tb,     0, 2)
        PROJ_STEP(tb + 1, 1, 0)
        PROJ_STEP(tb + 2, 2, 1)
    }
    // tail: t=30 (buf 0), t=31 (buf 1), no staging
    asm volatile("s_waitcnt vmcnt(4)" ::: "memory");
    __builtin_amdgcn_s_barrier();
    CFENCE;
    PROJ_COMP(0)
    asm volatile("s_waitcnt vmcnt(0)" ::: "memory");
    __builtin_amdgcn_s_barrier();
    CFENCE;
    PROJ_COMP(1)

    #pragma unroll
    for (int mg = 0; mg < 4; ++mg)
        #pragma unroll
        for (int ng = 0; ng < 4; ++ng)
            #pragma unroll
            for (int r = 0; r < 4; ++r) {
                int row = m0 + wr * 64 + mg * 16 + quad * 4 + r;
                int col = n0 + wc * 64 + ng * 16 + l16;
                if (!isV) {
                    float v = acc[mg][ng][r] + (z ? bk[col] : bq[col]);
                    QKh[(long)z * 4194304 + (long)row * 1024 + col] = f2bf(v);
                } else {
                    float v = acc[mg][ng][r] + bv[row];
                    int bcol = col >> 9, lc = col & 511;    // token -> (batch, local)
                    Vt[(long)bcol * 524288 + (long)row * 512 + lc] = (_Float16)v;
                }
            }
}

// ---------- K3: flash attention, m97-style cooperative LDS staging ----------
__global__ __launch_bounds__(256, 4)
void flash_attn6(const short* __restrict__ Q, const short* __restrict__ Kh,
                 const _Float16* __restrict__ Vt, const __half* __restrict__ G,
                 short* __restrict__ O) {
    const int tid = threadIdx.x;
    const int wave = tid >> 6, lane = tid & 63, quad = lane >> 4, l16 = lane & 15;
    const int qt = blockIdx.x, h = blockIdx.y, b = blockIdx.z;

    __shared__ __align__(16) short    Ks[64][72];        // [kv][d]
    __shared__ __align__(16) _Float16 Vs[64][72];        // [d][kv]
    __shared__ __align__(16) _Float16 Gs[64][72];        // [q][kv]
    __shared__ __align__(16) _Float16 Pbuf[4][16][72];   // per-wave private

    const int qrow = qt * 64 + wave * 16;
    const long qoff = ((long)(b * 512 + qrow + l16)) * 1024 + h * 64 + quad * 8;
    bf16x8 aq0 = *(const bf16x8*)(Q + qoff);
    bf16x8 aq1 = *(const bf16x8*)(Q + qoff + 32);

    const int sr0 = tid >> 3,         sc0 = (tid & 7) * 8;
    const int sr1 = (tid + 256) >> 3, sc1 = ((tid + 256) & 7) * 8;
    const short* Kbase = Kh + (long)(b * 512) * 1024 + h * 64;
    const _Float16* Vbase = Vt + (long)b * 524288 + (long)(h * 64) * 512;
    const _Float16* Gbase = (const _Float16*)G + ((long)((b * 16 + h) * 512 + qt * 64)) * 512;

    f32x4 oacc[4];
    #pragma unroll
    for (int r = 0; r < 4; ++r) oacc[r] = (f32x4){0.f, 0.f, 0.f, 0.f};
    float rs = 0.f;

    for (int kt = 0; kt < 8; ++kt) {
        __syncthreads();
        short8 k0 = *(const short8*)(Kbase + (long)(kt * 64 + sr0) * 1024 + sc0);
        short8 k1 = *(const short8*)(Kbase + (long)(kt * 64 + sr1) * 1024 + sc1);
        short8 v0 = *(const short8*)(Vbase + (long)sr0 * 512 + kt * 64 + sc0);
        short8 v1 = *(const short8*)(Vbase + (long)sr1 * 512 + kt * 64 + sc1);
        short8 g0 = *(const short8*)(Gbase + (long)sr0 * 512 + kt * 64 + sc0);
        short8 g1 = *(const short8*)(Gbase + (long)sr1 * 512 + kt * 64 + sc1);
        *(short8*)&Ks[sr0][sc0] = k0;
        *(short8*)&Ks[sr1][sc1] = k1;
        *(short8*)&Vs[sr0][sc0] = v0;
        *(short8*)&Vs[sr1][sc1] = v1;
        *(short8*)&Gs[sr0][sc0] = g0;
        *(short8*)&Gs[sr1][sc1] = g1;
        __syncthreads();

        f32x4 sc[4];
        #pragma unroll
        for (int nk = 0; nk < 4; ++nk) {
            bf16x8 bk0 = *(const bf16x8*)&Ks[nk * 16 + l16][quad * 8];
            bf16x8 bk1 = *(const bf16x8*)&Ks[nk * 16 + l16][32 + quad * 8];
            f32x4 s = (f32x4){0.f, 0.f, 0.f, 0.f};
            s = __builtin_amdgcn_mfma_f32_16x16x32_bf16(aq0, bk0, s, 0, 0, 0);
            s = __builtin_amdgcn_mfma_f32_16x16x32_bf16(aq1, bk1, s, 0, 0, 0);
            sc[nk] = s;
        }
        #pragma unroll
        for (int nk = 0; nk < 4; ++nk)
            #pragma unroll
            for (int r = 0; r < 4; ++r)
                Pbuf[wave][quad * 4 + r][nk * 16 + l16] = (_Float16)__expf(sc[nk][r] * 0.125f);
        f16x8 ep0 = *(const f16x8*)&Pbuf[wave][l16][quad * 8];
        f16x8 ep1 = *(const f16x8*)&Pbuf[wave][l16][32 + quad * 8];
        f16x8 gA = *(const f16x8*)&Gs[wave * 16 + l16][quad * 8];
        f16x8 gB = *(const f16x8*)&Gs[wave * 16 + l16][32 + quad * 8];
        f16x8 gp0 = ep0 * gA;
        f16x8 gp1 = ep1 * gB;
        float part = 0.f;
        #pragma unroll
        for (int j = 0; j < 8; ++j) part += (float)gp0[j] + (float)gp1[j];
        rs += part;
        #pragma unroll
        for (int n4 = 0; n4 < 4; ++n4) {
            f16x8 bv0 = *(const f16x8*)&Vs[n4 * 16 + l16][quad * 8];
            f16x8 bv1 = *(const f16x8*)&Vs[n4 * 16 + l16][32 + quad * 8];
            oacc[n4] = __builtin_amdgcn_mfma_f32_16x16x32_f16(gp0, bv0, oacc[n4], 0, 0, 0);
            oacc[n4] = __builtin_amdgcn_mfma_f32_16x16x32_f16(gp1, bv1, oacc[n4], 0, 0, 0);
        }
    }

    rs += __shfl_xor(rs, 16);
    rs += __shfl_xor(rs, 32);
    float li[4];
    #pragma unroll
    for (int r = 0; r < 4; ++r) li[r] = __shfl(rs, quad * 4 + r);

    #pragma unroll
    for (int n4 = 0; n4 < 4; ++n4)
        #pragma unroll
        for (int r = 0; r < 4; ++r) {
            float o = oacc[n4][r] / li[r];
            O[((long)(b * 512 + qrow + quad * 4 + r)) * 1024 + h * 64 + n4 * 16 + l16] = f2bf(o);
        }
}

// ---------- K4: Wo GEMM, 128x64 tiles, 3-buffer prefetch + XCD swizzle + T2 LDS swizzle ----------
#define GOUT_COMP(BC)                                                                  \
    {                                                                                  \
        bf16x8 a_[2], bb_[4];                                                          \
        _Pragma("unroll")                                                              \
        for (int g = 0; g < 2; ++g) {                                                  \
            int gl = (mw + g * 16 + l16) * 4 + quad;                                   \
            gl ^= (gl >> 3) & 7;                                                       \
            a_[g] = *(const bf16x8*)&As[BC][gl * 8];                                   \
        }                                                                              \
        _Pragma("unroll")                                                              \
        for (int g = 0; g < 4; ++g) {                                                  \
            int gl = (g * 16 + l16) * 4 + quad;                                        \
            gl ^= (gl >> 3) & 7;                                                       \
            bb_[g] = *(const bf16x8*)&Bs[BC][gl * 8];                                  \
        }                                                                              \
        _Pragma("unroll")                                                              \
        for (int mg = 0; mg < 2; ++mg)                                                 \
            _Pragma("unroll")                                                          \
            for (int ng = 0; ng < 4; ++ng)                                             \
                acc[mg][ng] = __builtin_amdgcn_mfma_f32_16x16x32_bf16(a_[mg], bb_[ng], acc[mg][ng], 0, 0, 0); \
    }

#define GOUT_STEP(T, BC, BS)                                                           \
    {                                                                                  \
        asm volatile("s_waitcnt vmcnt(3)" ::: "memory");                               \
        __builtin_amdgcn_s_barrier();                                                  \
        CFENCE;                                                                        \
        const int k1_ = ((T) + 2) * 32;                                                \
        load_lds16(ga0 + k1_, &As[BS][wb]);                                            \
        load_lds16(ga1 + k1_, &As[BS][2048 + wb]);                                     \
        load_lds16(gb0 + k1_, &Bs[BS][wb]);                                            \
        GOUT_COMP(BC)                                                                  \
    }

__global__ __launch_bounds__(256, 4)
void gemm_out5(const short* __restrict__ Hd, const short* __restrict__ wob,
               const float* __restrict__ bo, float* __restrict__ out) {
    __shared__ __align__(16) short As[3][4096];   // 3 x [128][32] (swizzled granules)
    __shared__ __align__(16) short Bs[3][2048];   // 3 x [64][32]
    const int tid = threadIdx.x;
    const int wave = tid >> 6, lane = tid & 63, quad = lane >> 4, l16 = lane & 15;
    // 512 blocks = 8 x 64-chunk XCD swizzle; FLAT 512-block grid required.
    const int bid = (blockIdx.x & 7) * 64 + (blockIdx.x >> 3);
    const int m0 = (bid >> 4) * 128, n0 = (bid & 15) * 64;
    const short* Ap = Hd + (long)m0 * 1024;
    const short* Bp = wob + (long)n0 * 1024;

    f32x4 acc[2][4];
    #pragma unroll
    for (int mg = 0; mg < 2; ++mg)
        #pragma unroll
        for (int ng = 0; ng < 4; ++ng) acc[mg][ng] = (f32x4){0.f, 0.f, 0.f, 0.f};

    const int lane6 = tid & 63;
    const int lj = lane6 ^ ((lane6 >> 3) & 7);
    const int r0 = wave * 16 + (lj >> 2), kk = (lj & 3) * 8;
    const short* ga0 = Ap + (long)r0 * 1024 + kk;
    const short* ga1 = Ap + (long)(64 + r0) * 1024 + kk;
    const short* gb0 = Bp + (long)r0 * 1024 + kk;
    const int wb = wave * 512;
    const int mw = wave * 32;

    // prologue: stage tiles 0 and 1
    load_lds16(ga0, &As[0][wb]);
    load_lds16(ga1, &As[0][2048 + wb]);
    load_lds16(gb0, &Bs[0][wb]);
    load_lds16(ga0 + 32, &As[1][wb]);
    load_lds16(ga1 + 32, &As[1][2048 + wb]);
    load_lds16(gb0 + 32, &Bs[1][wb]);

    for (int tb = 0; tb < 30; tb += 3) {
        GOUT_STEP(tb,     0, 2)
        GOUT_STEP(tb + 1, 1, 0)
        GOUT_STEP(tb + 2, 2, 1)
    }
    asm volatile("s_waitcnt vmcnt(3)" ::: "memory");
    __builtin_amdgcn_s_barrier();
    CFENCE;
    GOUT_COMP(0)
    asm volatile("s_waitcnt vmcnt(0)" ::: "memory");
    __builtin_amdgcn_s_barrier();
    CFENCE;
    GOUT_COMP(1)

    #pragma unroll
    for (int mg = 0; mg < 2; ++mg)
        #pragma unroll
        for (int ng = 0; ng < 4; ++ng)
            #pragma unroll
            for (int r = 0; r < 4; ++r) {
                int row = m0 + mw + mg * 16 + quad * 4 + r;
                int col = n0 + ng * 16 + l16;
                out[(long)row * 1024 + col] = acc[mg][ng][r] + bo[col];
            }
}

// ---------- launch ----------
extern "C" void kernel_launch(void* const* d_in, const int* in_sizes, int n_in,
                              void* d_out, int out_size, void* d_ws, size_t ws_size,
                              hipStream_t stream) {
    const float* queries = (const float*)d_in[0];
    const float* keys    = (const float*)d_in[1];
    const float* values  = (const float*)d_in[2];
    const float* boxes   = (const float*)d_in[3];
    const float* bq = (const float*)d_in[5];
    const float* bk = (const float*)d_in[7];
    const float* bv = (const float*)d_in[9];
    const float* bo = (const float*)d_in[11];
    const float* Wg = (const float*)d_in[12];
    const float* bg = (const float*)d_in[13];

    char* ws = (char*)d_ws;
    short* qbf = (short*)(ws + 0);
    short* kbf = (short*)(ws + 8388608);
    short* vbf = (short*)(ws + 16777216);
    short* wqb = (short*)(ws + 25165824);    // wqb/wkb adjacent (z-stride 1048576 elems)
    short* wkb = (short*)(ws + 27262976);
    short* wvb = (short*)(ws + 29360128);
    short* wob = (short*)(ws + 31457280);
    short* Qh  = (short*)(ws + 33554432);    // Qh/Kh adjacent (z-stride 4194304 elems)
    _Float16* Vt = (_Float16*)(ws + 50331648);  // [b][1024 out][512 tok] f16
    short* Hd  = (short*)(ws + 58720256);    // hidden [4096][1024]
    __half* G  = (__half*)(ws + 67108864);   // g [b][h][512][512] f16, 67 MB
    _Float16* Wgh = (_Float16*)(ws + 33554432);  // overlaps Qh (dead before proj)

    convert_qkv<<<dim3(4096, 3), 256, 0, stream>>>(queries, keys, values, qbf, kbf, vbf);
    convert_w4<<<dim3(1024, 4), 256, 0, stream>>>((const float*)d_in[4], (const float*)d_in[6],
                                                  (const float*)d_in[8], (const float*)d_in[10],
                                                  wqb, wkb, wvb, wob);
    convert_f32_f16<<<4, 256, 0, stream>>>(Wg, Wgh, 1024);

    geom_kernel4<<<dim3(8, 64, 8), 256, 0, stream>>>(boxes, Wgh, bg, G);

    // all projections: 768 blocks, 128x128 tiles, 3-deep prefetch, XCD swizzle
    proj_all7<<<768, 256, 0, stream>>>(qbf, wqb, wvb, vbf, bq, bk, bv, Qh, Vt);

    flash_attn6<<<dim3(8, 16, 8), 256, 0, stream>>>(Qh, Qh + 4194304, Vt, G, Hd);

    // output projection -> f32 + bias, FLAT 512-block grid
    gemm_out5<<<512, 256, 0, stream>>>(Hd, wob, bo, (float*)d_out);
}

// Round 11
// 254.784 us; speedup vs baseline: 1.0819x; 1.0080x over previous
//
#include <hip/hip_runtime.h>
#include <hip/hip_bf16.h>
#include <hip/hip_fp16.h>

// ---------- common types ----------
typedef __attribute__((ext_vector_type(8))) short bf16x8;      // 8 bf16 = 4 VGPR (MFMA A/B frag)
typedef __attribute__((ext_vector_type(8))) _Float16 f16x8;    // 8 f16  = 4 VGPR (MFMA A/B frag)
typedef __attribute__((ext_vector_type(4))) float f32x4;       // MFMA C/D frag
typedef __attribute__((ext_vector_type(8))) short short8;      // 16B chunk

__device__ __forceinline__ short f2bf(float x) {
    unsigned u = __builtin_bit_cast(unsigned, x);
    u += 0x7fffu + ((u >> 16) & 1u);          // RNE
    return (short)(u >> 16);
}

// async global->LDS, 16B per lane. lds dst must be wave-uniform base; HW scatters lane*16.
__device__ __forceinline__ void load_lds16(const void* g, void* l) {
    __builtin_amdgcn_global_load_lds((const __attribute__((address_space(1))) unsigned int*)g,
                                     (__attribute__((address_space(3))) unsigned int*)l, 16, 0, 0);
}

// ---------- K0: fused converts ----------
__global__ void convert_qkv(const float* __restrict__ q, const float* __restrict__ k,
                            const float* __restrict__ v, short* __restrict__ qo,
                            short* __restrict__ ko, short* __restrict__ vo) {
    int i = blockIdx.x * 256 + threadIdx.x;   // 1048576 float4 per tensor, grid (4096,3)
    const float* s = blockIdx.y == 0 ? q : blockIdx.y == 1 ? k : v;
    short* d = blockIdx.y == 0 ? qo : blockIdx.y == 1 ? ko : vo;
    float4 val = reinterpret_cast<const float4*>(s)[i];
    short4 o; o.x = f2bf(val.x); o.y = f2bf(val.y); o.z = f2bf(val.z); o.w = f2bf(val.w);
    reinterpret_cast<short4*>(d)[i] = o;
}

__global__ void convert_w4(const float* __restrict__ w0, const float* __restrict__ w1,
                           const float* __restrict__ w2, const float* __restrict__ w3,
                           short* __restrict__ o0, short* __restrict__ o1,
                           short* __restrict__ o2, short* __restrict__ o3) {
    int i = blockIdx.x * 256 + threadIdx.x;   // 262144 float4 per tensor, grid (1024,4)
    const float* s = blockIdx.y == 0 ? w0 : blockIdx.y == 1 ? w1 : blockIdx.y == 2 ? w2 : w3;
    short* d = blockIdx.y == 0 ? o0 : blockIdx.y == 1 ? o1 : blockIdx.y == 2 ? o2 : o3;
    float4 val = reinterpret_cast<const float4*>(s)[i];
    short4 o; o.x = f2bf(val.x); o.y = f2bf(val.y); o.z = f2bf(val.z); o.w = f2bf(val.w);
    reinterpret_cast<short4*>(d)[i] = o;
}

__global__ void convert_f32_f16(const float* __restrict__ src, _Float16* __restrict__ dst, int n) {
    int i = blockIdx.x * blockDim.x + threadIdx.x;
    if (i < n) dst[i] = (_Float16)src[i];
}

// ---------- K1: geometry bias. 64 m x 8 n per block (PROVEN r9 version) ----------
// r7/r8/r10 lesson: every cross-lane handoff through LDS must have a barrier (or be a
// compiler-visible shuffle) — geom variants that relaxed this raced or wobbled. This
// version keeps the write -> __syncthreads -> read discipline everywhere. Do not relax.
__global__ __launch_bounds__(256)
void geom_kernel4(const float* __restrict__ boxes, const _Float16* __restrict__ Wgh,
                  const float* __restrict__ bg, __half* __restrict__ G) {
    const int tid = threadIdx.x;
    const int wave = tid >> 6, lane = tid & 63, quad = lane >> 4, l16 = lane & 15;
    const int m0 = blockIdx.x * 64;
    const int n0 = blockIdx.y * 8;
    const int b = blockIdx.z;

    __shared__ __align__(16) _Float16 feat[4][16][72];
    __shared__ __align__(16) _Float16 gbuf[16][68];

    const int p = lane >> 2, c = lane & 3;
    const int m = m0 + wave * 16 + p;

    // m-side (per-thread, hoisted)
    float4 bm = reinterpret_cast<const float4*>(boxes)[b * 512 + m];
    float cxm = (bm.x + bm.z) * 0.5f, cym = (bm.y + bm.w) * 0.5f;
    float wm = bm.z - bm.x + 1.0f, hm = bm.w - bm.y + 1.0f;
    float lwm = __logf(wm), lhm = __logf(hm);

    // Wg fragments (constant across n) + bias
    f16x8 wb0 = *(const f16x8*)(Wgh + l16 * 64 + quad * 8);
    f16x8 wb1 = *(const f16x8*)(Wgh + l16 * 64 + 32 + quad * 8);
    float bgv = bg[l16];

    const float dm[8] = {1.0f, 0.42169651f, 0.17782794f, 0.07498942f,
                         0.03162278f, 0.01333521f, 0.00562341f, 0.00237137f};
    const int h = tid >> 4, seg = tid & 15;

    for (int ni = 0; ni < 8; ++ni) {
        const int n = n0 + ni;
        float4 bn = reinterpret_cast<const float4*>(boxes)[b * 512 + n];   // uniform
        float cxn = (bn.x + bn.z) * 0.5f, cyn = (bn.y + bn.w) * 0.5f;
        float wn = bn.z - bn.x + 1.0f, hn = bn.w - bn.y + 1.0f;
        float lwn = __logf(wn), lhn = __logf(hn);

        // channel c: 0:|cxn-cxm|/wn  1:|cyn-cym|/hn  2:wn/wm  3:hn/hm
        float numa = (c == 1) ? fabsf(cyn - cym) : fabsf(cxn - cxm);
        float pl = fmaxf(__logf(numa) - ((c == 1) ? lhn : lwn), -6.9077552790f);  // log(1e-3)
        float sl = (c == 3) ? (lhn - lhm) : (lwn - lwm);
        float pos = ((c < 2) ? pl : sl) * 100.0f;

        f16x8 sv8, cv8;
        #pragma unroll
        for (int f = 0; f < 8; ++f) {
            float th = pos * dm[f];
            sv8[f] = (_Float16)__sinf(th);
            cv8[f] = (_Float16)__cosf(th);
        }
        *(f16x8*)&feat[wave][p][c * 8]      = sv8;
        *(f16x8*)&feat[wave][p][32 + c * 8] = cv8;

        __syncthreads();

        f16x8 a0 = *(const f16x8*)&feat[wave][l16][quad * 8];
        f16x8 a1 = *(const f16x8*)&feat[wave][l16][32 + quad * 8];
        f32x4 acc = (f32x4){0.f, 0.f, 0.f, 0.f};
        acc = __builtin_amdgcn_mfma_f32_16x16x32_f16(a0, wb0, acc, 0, 0, 0);
        acc = __builtin_amdgcn_mfma_f32_16x16x32_f16(a1, wb1, acc, 0, 0, 0);

        #pragma unroll
        for (int rr = 0; rr < 4; ++rr) {
            float g = fmaxf(acc[rr] + bgv, 1e-6f);        // relu + clip; store g itself
            gbuf[l16][wave * 16 + quad * 4 + rr] = (_Float16)g;
        }
        __syncthreads();

        ushort4 v = *(const ushort4*)&gbuf[h][seg * 4];
        *(ushort4*)&G[((long)((b * 16 + h) * 512 + n)) * 512 + m0 + seg * 4] = v;
    }
}

// ---------- K2: projections, 128x128 tiles, 3-buffer 2-ahead prefetch + XCD swizzle ----------
// CFENCE after each raw s_barrier: __builtin_amdgcn_s_barrier() is IntrNoMem — not a
// compiler memory fence. The fence pins staging/ds_reads on the correct side of the
// barrier; zero instructions emitted.
#define CFENCE asm volatile("" ::: "memory")

#define PROJ_COMP(BC)                                                                  \
    {                                                                                  \
        bf16x8 a_[4], bb_[4];                                                          \
        _Pragma("unroll")                                                              \
        for (int g = 0; g < 4; ++g)                                                    \
            a_[g] = *(const bf16x8*)&As[BC][(wr * 64 + g * 16 + l16) * 32 + quad * 8]; \
        _Pragma("unroll")                                                              \
        for (int g = 0; g < 4; ++g)                                                    \
            bb_[g] = *(const bf16x8*)&Bs[BC][(wc * 64 + g * 16 + l16) * 32 + quad * 8];\
        _Pragma("unroll")                                                              \
        for (int mg = 0; mg < 4; ++mg)                                                 \
            _Pragma("unroll")                                                          \
            for (int ng = 0; ng < 4; ++ng)                                             \
                acc[mg][ng] = __builtin_amdgcn_mfma_f32_16x16x32_bf16(a_[mg], bb_[ng], acc[mg][ng], 0, 0, 0); \
    }

#define PROJ_STEP(T, BC, BS)                                                           \
    {                                                                                  \
        asm volatile("s_waitcnt vmcnt(4)" ::: "memory");                               \
        __builtin_amdgcn_s_barrier();                                                  \
        CFENCE;                                                                        \
        const int k1_ = ((T) + 2) * 32;                                                \
        load_lds16(ga0 + k1_, &As[BS][wb]);                                            \
        load_lds16(ga1 + k1_, &As[BS][2048 + wb]);                                     \
        load_lds16(gb0 + k1_, &Bs[BS][wb]);                                            \
        load_lds16(gb1 + k1_, &Bs[BS][2048 + wb]);                                     \
        PROJ_COMP(BC)                                                                  \
    }

__global__ __launch_bounds__(256, 3)
void proj_all7(const short* __restrict__ qkbf, const short* __restrict__ wqkb,
               const short* __restrict__ wvb, const short* __restrict__ vbf,
               const float* __restrict__ bq, const float* __restrict__ bk,
               const float* __restrict__ bv,
               short* __restrict__ QKh, _Float16* __restrict__ Vt) {
    __shared__ __align__(16) short As[3][4096];   // 3 x [128][32]
    __shared__ __align__(16) short Bs[3][4096];
    const int tid = threadIdx.x;
    const int wave = tid >> 6, lane = tid & 63, quad = lane >> 4, l16 = lane & 15;
    // T1 XCD swizzle: 768 blocks = 8 XCDs x 96-chunk (bijective).
    const int bid = (blockIdx.x & 7) * 96 + (blockIdx.x >> 3);

    const short *Ap, *Bp;
    int m0, n0, z = 0;
    bool isV = bid >= 512;
    if (!isV) {
        z = bid >> 8;
        int t = bid & 255;
        n0 = (t & 7) * 128; m0 = (t >> 3) * 128;      // 8 consecutive share token panel
        Ap = qkbf + (long)z * 4194304 + (long)m0 * 1024;
        Bp = wqkb + (long)z * 1048576 + (long)n0 * 1024;
    } else {
        int t = bid - 512;
        m0 = (t & 7) * 128; n0 = (t >> 3) * 128;      // 8 consecutive share token panel (vbf)
        Ap = wvb + (long)m0 * 1024;
        Bp = vbf + (long)n0 * 1024;
    }

    f32x4 acc[4][4];
    #pragma unroll
    for (int mg = 0; mg < 4; ++mg)
        #pragma unroll
        for (int ng = 0; ng < 4; ++ng) acc[mg][ng] = (f32x4){0.f, 0.f, 0.f, 0.f};

    const int r0 = tid >> 2, kk = (tid & 3) * 8;
    const short* ga0 = Ap + (long)r0 * 1024 + kk;
    const short* ga1 = Ap + (long)(64 + r0) * 1024 + kk;
    const short* gb0 = Bp + (long)r0 * 1024 + kk;
    const short* gb1 = Bp + (long)(64 + r0) * 1024 + kk;
    const int wb = wave * 512;
    const int wr = wave >> 1, wc = wave & 1;   // 2x2 wave grid, 64x64 per wave

    // prologue: stage tiles 0 and 1 (tile-0 loads issued first => oldest for vmcnt)
    load_lds16(ga0, &As[0][wb]);
    load_lds16(ga1, &As[0][2048 + wb]);
    load_lds16(gb0, &Bs[0][wb]);
    load_lds16(gb1, &Bs[0][2048 + wb]);
    load_lds16(ga0 + 32, &As[1][wb]);
    load_lds16(ga1 + 32, &As[1][2048 + wb]);
    load_lds16(gb0 + 32, &Bs[1][wb]);
    load_lds16(gb1 + 32, &Bs[1][2048 + wb]);

    for (int tb = 0; tb < 30; tb += 3) {   // steps 0..29, staging tiles 2..31
        PROJ_STEP(tb,     0, 2)
        PROJ_STEP(tb + 1, 1, 0)
        PROJ_STEP(tb + 2, 2, 1)
    }
    // tail: t=30 (buf 0), t=31 (buf 1), no staging
    asm volatile("s_waitcnt vmcnt(4)" ::: "memory");
    __builtin_amdgcn_s_barrier();
    CFENCE;
    PROJ_COMP(0)
    asm volatile("s_waitcnt vmcnt(0)" ::: "memory");
    __builtin_amdgcn_s_barrier();
    CFENCE;
    PROJ_COMP(1)

    #pragma unroll
    for (int mg = 0; mg < 4; ++mg)
        #pragma unroll
        for (int ng = 0; ng < 4; ++ng)
            #pragma unroll
            for (int r = 0; r < 4; ++r) {
                int row = m0 + wr * 64 + mg * 16 + quad * 4 + r;
                int col = n0 + wc * 64 + ng * 16 + l16;
                if (!isV) {
                    float v = acc[mg][ng][r] + (z ? bk[col] : bq[col]);
                    QKh[(long)z * 4194304 + (long)row * 1024 + col] = f2bf(v);
                } else {
                    float v = acc[mg][ng][r] + bv[row];
                    int bcol = col >> 9, lc = col & 511;    // token -> (batch, local)
                    Vt[(long)bcol * 524288 + (long)row * 512 + lc] = (_Float16)v;
                }
            }
}

// ---------- K3: flash attention, m97-style cooperative LDS staging ----------
// HARDENING (r10): Pbuf is a cross-lane handoff through LDS (write rows quad*4+r,
// read rows l16) that previously relied on alias-analysis keeping program order —
// fragile under codegen-context changes (rule #19). A __syncthreads between write
// and read makes the ordering explicit; the loop-top barrier separates the read
// from the NEXT iteration's write. Numerically identical.
__global__ __launch_bounds__(256, 4)
void flash_attn6(const short* __restrict__ Q, const short* __restrict__ Kh,
                 const _Float16* __restrict__ Vt, const __half* __restrict__ G,
                 short* __restrict__ O) {
    const int tid = threadIdx.x;
    const int wave = tid >> 6, lane = tid & 63, quad = lane >> 4, l16 = lane & 15;
    const int qt = blockIdx.x, h = blockIdx.y, b = blockIdx.z;

    __shared__ __align__(16) short    Ks[64][72];        // [kv][d]
    __shared__ __align__(16) _Float16 Vs[64][72];        // [d][kv]
    __shared__ __align__(16) _Float16 Gs[64][72];        // [q][kv]
    __shared__ __align__(16) _Float16 Pbuf[4][16][72];   // per-wave private

    const int qrow = qt * 64 + wave * 16;
    const long qoff = ((long)(b * 512 + qrow + l16)) * 1024 + h * 64 + quad * 8;
    bf16x8 aq0 = *(const bf16x8*)(Q + qoff);
    bf16x8 aq1 = *(const bf16x8*)(Q + qoff + 32);

    const int sr0 = tid >> 3,         sc0 = (tid & 7) * 8;
    const int sr1 = (tid + 256) >> 3, sc1 = ((tid + 256) & 7) * 8;
    const short* Kbase = Kh + (long)(b * 512) * 1024 + h * 64;
    const _Float16* Vbase = Vt + (long)b * 524288 + (long)(h * 64) * 512;
    const _Float16* Gbase = (const _Float16*)G + ((long)((b * 16 + h) * 512 + qt * 64)) * 512;

    f32x4 oacc[4];
    #pragma unroll
    for (int r = 0; r < 4; ++r) oacc[r] = (f32x4){0.f, 0.f, 0.f, 0.f};
    float rs = 0.f;

    for (int kt = 0; kt < 8; ++kt) {
        __syncthreads();
        short8 k0 = *(const short8*)(Kbase + (long)(kt * 64 + sr0) * 1024 + sc0);
        short8 k1 = *(const short8*)(Kbase + (long)(kt * 64 + sr1) * 1024 + sc1);
        short8 v0 = *(const short8*)(Vbase + (long)sr0 * 512 + kt * 64 + sc0);
        short8 v1 = *(const short8*)(Vbase + (long)sr1 * 512 + kt * 64 + sc1);
        short8 g0 = *(const short8*)(Gbase + (long)sr0 * 512 + kt * 64 + sc0);
        short8 g1 = *(const short8*)(Gbase + (long)sr1 * 512 + kt * 64 + sc1);
        *(short8*)&Ks[sr0][sc0] = k0;
        *(short8*)&Ks[sr1][sc1] = k1;
        *(short8*)&Vs[sr0][sc0] = v0;
        *(short8*)&Vs[sr1][sc1] = v1;
        *(short8*)&Gs[sr0][sc0] = g0;
        *(short8*)&Gs[sr1][sc1] = g1;
        __syncthreads();

        f32x4 sc[4];
        #pragma unroll
        for (int nk = 0; nk < 4; ++nk) {
            bf16x8 bk0 = *(const bf16x8*)&Ks[nk * 16 + l16][quad * 8];
            bf16x8 bk1 = *(const bf16x8*)&Ks[nk * 16 + l16][32 + quad * 8];
            f32x4 s = (f32x4){0.f, 0.f, 0.f, 0.f};
            s = __builtin_amdgcn_mfma_f32_16x16x32_bf16(aq0, bk0, s, 0, 0, 0);
            s = __builtin_amdgcn_mfma_f32_16x16x32_bf16(aq1, bk1, s, 0, 0, 0);
            sc[nk] = s;
        }
        #pragma unroll
        for (int nk = 0; nk < 4; ++nk)
            #pragma unroll
            for (int r = 0; r < 4; ++r)
                Pbuf[wave][quad * 4 + r][nk * 16 + l16] = (_Float16)__expf(sc[nk][r] * 0.125f);
        __syncthreads();   // explicit write->read ordering for the Pbuf cross-lane handoff
        f16x8 ep0 = *(const f16x8*)&Pbuf[wave][l16][quad * 8];
        f16x8 ep1 = *(const f16x8*)&Pbuf[wave][l16][32 + quad * 8];
        f16x8 gA = *(const f16x8*)&Gs[wave * 16 + l16][quad * 8];
        f16x8 gB = *(const f16x8*)&Gs[wave * 16 + l16][32 + quad * 8];
        f16x8 gp0 = ep0 * gA;
        f16x8 gp1 = ep1 * gB;
        float part = 0.f;
        #pragma unroll
        for (int j = 0; j < 8; ++j) part += (float)gp0[j] + (float)gp1[j];
        rs += part;
        #pragma unroll
        for (int n4 = 0; n4 < 4; ++n4) {
            f16x8 bv0 = *(const f16x8*)&Vs[n4 * 16 + l16][quad * 8];
            f16x8 bv1 = *(const f16x8*)&Vs[n4 * 16 + l16][32 + quad * 8];
            oacc[n4] = __builtin_amdgcn_mfma_f32_16x16x32_f16(gp0, bv0, oacc[n4], 0, 0, 0);
            oacc[n4] = __builtin_amdgcn_mfma_f32_16x16x32_f16(gp1, bv1, oacc[n4], 0, 0, 0);
        }
    }

    rs += __shfl_xor(rs, 16);
    rs += __shfl_xor(rs, 32);
    float li[4];
    #pragma unroll
    for (int r = 0; r < 4; ++r) li[r] = __shfl(rs, quad * 4 + r);

    #pragma unroll
    for (int n4 = 0; n4 < 4; ++n4)
        #pragma unroll
        for (int r = 0; r < 4; ++r) {
            float o = oacc[n4][r] / li[r];
            O[((long)(b * 512 + qrow + quad * 4 + r)) * 1024 + h * 64 + n4 * 16 + l16] = f2bf(o);
        }
}

// ---------- K4: Wo GEMM, 128x64 tiles, 3-buffer prefetch + XCD swizzle + T2 LDS swizzle ----------
#define GOUT_COMP(BC)                                                                  \
    {                                                                                  \
        bf16x8 a_[2], bb_[4];                                                          \
        _Pragma("unroll")                                                              \
        for (int g = 0; g < 2; ++g) {                                                  \
            int gl = (mw + g * 16 + l16) * 4 + quad;                                   \
            gl ^= (gl >> 3) & 7;                                                       \
            a_[g] = *(const bf16x8*)&As[BC][gl * 8];                                   \
        }                                                                              \
        _Pragma("unroll")                                                              \
        for (int g = 0; g < 4; ++g) {                                                  \
            int gl = (g * 16 + l16) * 4 + quad;                                        \
            gl ^= (gl >> 3) & 7;                                                       \
            bb_[g] = *(const bf16x8*)&Bs[BC][gl * 8];                                  \
        }                                                                              \
        _Pragma("unroll")                                                              \
        for (int mg = 0; mg < 2; ++mg)                                                 \
            _Pragma("unroll")                                                          \
            for (int ng = 0; ng < 4; ++ng)                                             \
                acc[mg][ng] = __builtin_amdgcn_mfma_f32_16x16x32_bf16(a_[mg], bb_[ng], acc[mg][ng], 0, 0, 0); \
    }

#define GOUT_STEP(T, BC, BS)                                                           \
    {                                                                                  \
        asm volatile("s_waitcnt vmcnt(3)" ::: "memory");                               \
        __builtin_amdgcn_s_barrier();                                                  \
        CFENCE;                                                                        \
        const int k1_ = ((T) + 2) * 32;                                                \
        load_lds16(ga0 + k1_, &As[BS][wb]);                                            \
        load_lds16(ga1 + k1_, &As[BS][2048 + wb]);                                     \
        load_lds16(gb0 + k1_, &Bs[BS][wb]);                                            \
        GOUT_COMP(BC)                                                                  \
    }

__global__ __launch_bounds__(256, 4)
void gemm_out5(const short* __restrict__ Hd, const short* __restrict__ wob,
               const float* __restrict__ bo, float* __restrict__ out) {
    __shared__ __align__(16) short As[3][4096];   // 3 x [128][32] (swizzled granules)
    __shared__ __align__(16) short Bs[3][2048];   // 3 x [64][32]
    const int tid = threadIdx.x;
    const int wave = tid >> 6, lane = tid & 63, quad = lane >> 4, l16 = lane & 15;
    // 512 blocks = 8 x 64-chunk XCD swizzle; FLAT 512-block grid required.
    const int bid = (blockIdx.x & 7) * 64 + (blockIdx.x >> 3);
    const int m0 = (bid >> 4) * 128, n0 = (bid & 15) * 64;
    const short* Ap = Hd + (long)m0 * 1024;
    const short* Bp = wob + (long)n0 * 1024;

    f32x4 acc[2][4];
    #pragma unroll
    for (int mg = 0; mg < 2; ++mg)
        #pragma unroll
        for (int ng = 0; ng < 4; ++ng) acc[mg][ng] = (f32x4){0.f, 0.f, 0.f, 0.f};

    const int lane6 = tid & 63;
    const int lj = lane6 ^ ((lane6 >> 3) & 7);
    const int r0 = wave * 16 + (lj >> 2), kk = (lj & 3) * 8;
    const short* ga0 = Ap + (long)r0 * 1024 + kk;
    const short* ga1 = Ap + (long)(64 + r0) * 1024 + kk;
    const short* gb0 = Bp + (long)r0 * 1024 + kk;
    const int wb = wave * 512;
    const int mw = wave * 32;

    // prologue: stage tiles 0 and 1
    load_lds16(ga0, &As[0][wb]);
    load_lds16(ga1, &As[0][2048 + wb]);
    load_lds16(gb0, &Bs[0][wb]);
    load_lds16(ga0 + 32, &As[1][wb]);
    load_lds16(ga1 + 32, &As[1][2048 + wb]);
    load_lds16(gb0 + 32, &Bs[1][wb]);

    for (int tb = 0; tb < 30; tb += 3) {
        GOUT_STEP(tb,     0, 2)
        GOUT_STEP(tb + 1, 1, 0)
        GOUT_STEP(tb + 2, 2, 1)
    }
    asm volatile("s_waitcnt vmcnt(3)" ::: "memory");
    __builtin_amdgcn_s_barrier();
    CFENCE;
    GOUT_COMP(0)
    asm volatile("s_waitcnt vmcnt(0)" ::: "memory");
    __builtin_amdgcn_s_barrier();
    CFENCE;
    GOUT_COMP(1)

    #pragma unroll
    for (int mg = 0; mg < 2; ++mg)
        #pragma unroll
        for (int ng = 0; ng < 4; ++ng)
            #pragma unroll
            for (int r = 0; r < 4; ++r) {
                int row = m0 + mw + mg * 16 + quad * 4 + r;
                int col = n0 + ng * 16 + l16;
                out[(long)row * 1024 + col] = acc[mg][ng][r] + bo[col];
            }
}

// ---------- launch ----------
extern "C" void kernel_launch(void* const* d_in, const int* in_sizes, int n_in,
                              void* d_out, int out_size, void* d_ws, size_t ws_size,
                              hipStream_t stream) {
    const float* queries = (const float*)d_in[0];
    const float* keys    = (const float*)d_in[1];
    const float* values  = (const float*)d_in[2];
    const float* boxes   = (const float*)d_in[3];
    const float* bq = (const float*)d_in[5];
    const float* bk = (const float*)d_in[7];
    const float* bv = (const float*)d_in[9];
    const float* bo = (const float*)d_in[11];
    const float* Wg = (const float*)d_in[12];
    const float* bg = (const float*)d_in[13];

    char* ws = (char*)d_ws;
    short* qbf = (short*)(ws + 0);
    short* kbf = (short*)(ws + 8388608);
    short* vbf = (short*)(ws + 16777216);
    short* wqb = (short*)(ws + 25165824);    // wqb/wkb adjacent (z-stride 1048576 elems)
    short* wkb = (short*)(ws + 27262976);
    short* wvb = (short*)(ws + 29360128);
    short* wob = (short*)(ws + 31457280);
    short* Qh  = (short*)(ws + 33554432);    // Qh/Kh adjacent (z-stride 4194304 elems)
    _Float16* Vt = (_Float16*)(ws + 50331648);  // [b][1024 out][512 tok] f16
    short* Hd  = (short*)(ws + 58720256);    // hidden [4096][1024]
    __half* G  = (__half*)(ws + 67108864);   // g [b][h][512][512] f16, 67 MB
    _Float16* Wgh = (_Float16*)(ws + 33554432);  // overlaps Qh (dead before proj)

    convert_qkv<<<dim3(4096, 3), 256, 0, stream>>>(queries, keys, values, qbf, kbf, vbf);
    convert_w4<<<dim3(1024, 4), 256, 0, stream>>>((const float*)d_in[4], (const float*)d_in[6],
                                                  (const float*)d_in[8], (const float*)d_in[10],
                                                  wqb, wkb, wvb, wob);
    convert_f32_f16<<<4, 256, 0, stream>>>(Wg, Wgh, 1024);

    geom_kernel4<<<dim3(8, 64, 8), 256, 0, stream>>>(boxes, Wgh, bg, G);

    // all projections: 768 blocks, 128x128 tiles, 3-deep prefetch, XCD swizzle
    proj_all7<<<768, 256, 0, stream>>>(qbf, wqb, wvb, vbf, bq, bk, bv, Qh, Vt);

    flash_attn6<<<dim3(8, 16, 8), 256, 0, stream>>>(Qh, Qh + 4194304, Vt, G, Hd);

    // output projection -> f32 + bias, FLAT 512-block grid
    gemm_out5<<<512, 256, 0, stream>>>(Hd, wob, bo, (float*)d_out);
}